// Round 1
// baseline (1610.446 us; speedup 1.0000x reference)
//
#include <hip/hip_runtime.h>
#include <hip/hip_bf16.h>
#include <math.h>

#define B_   2
#define S_   2048
#define D_   1024
#define H_   16
#define DK_  64
#define NQKV 3072          // 3*H*DK
#define M_   (B_ * S_)     // 4096

// ---------------- RoPE cos/sin table (double-precision trig) ----------------
// theta_i(pos) = pos / 10000^(i/32), i = 0..31
__global__ void rope_table_kernel(const int* __restrict__ pos,
                                  float* __restrict__ ct,
                                  float* __restrict__ st) {
  int idx = blockIdx.x * blockDim.x + threadIdx.x;   // S*32 threads
  int i = idx & 31;
  int s = idx >> 5;
  if (s >= S_) return;
  double p = (double)pos[s];
  double freq = pow(10000.0, -(double)i / 32.0);
  double t = p * freq;
  ct[idx] = (float)cos(t);
  st[idx] = (float)sin(t);
}

// ---------------- generic f32 GEMM: C[M][N] = A[M][K] * Bm[N][K]^T ----------
// Both operands row-major with K contiguous (exactly the layout of x/weight
// and att/wo_weight). 64x64 tile, BK=16, 256 threads, 4x4 per thread.
__global__ __launch_bounds__(256) void gemm_nt_f32(const float* __restrict__ A,
                                                   const float* __restrict__ Bm,
                                                   float* __restrict__ C,
                                                   int Md, int Nd, int Kd) {
  (void)Md;
  __shared__ float As[16][68];   // [k][m], pad 68 keeps float4 reads 16B-aligned
  __shared__ float Bs[16][68];   // [k][n]
  const int tx = threadIdx.x;    // 16
  const int ty = threadIdx.y;    // 16
  const int t  = ty * 16 + tx;
  const int m0 = blockIdx.y * 64;
  const int n0 = blockIdx.x * 64;
  const int lr = t >> 2;         // 0..63 tile row
  const int lc = (t & 3) * 4;    // 0,4,8,12 k-offset
  const float* Ap = A + (size_t)(m0 + lr) * Kd + lc;
  const float* Bp = Bm + (size_t)(n0 + lr) * Kd + lc;

  float acc[4][4] = {};
  for (int k0 = 0; k0 < Kd; k0 += 16) {
    float4 av = *(const float4*)(Ap + k0);
    float4 bv = *(const float4*)(Bp + k0);
    __syncthreads();   // previous iteration's reads done before overwrite
    As[lc + 0][lr] = av.x; As[lc + 1][lr] = av.y;
    As[lc + 2][lr] = av.z; As[lc + 3][lr] = av.w;
    Bs[lc + 0][lr] = bv.x; Bs[lc + 1][lr] = bv.y;
    Bs[lc + 2][lr] = bv.z; Bs[lc + 3][lr] = bv.w;
    __syncthreads();
#pragma unroll
    for (int kk = 0; kk < 16; ++kk) {
      float4 a4 = *(const float4*)&As[kk][ty * 4];
      float4 b4 = *(const float4*)&Bs[kk][tx * 4];
      acc[0][0] = fmaf(a4.x, b4.x, acc[0][0]);
      acc[0][1] = fmaf(a4.x, b4.y, acc[0][1]);
      acc[0][2] = fmaf(a4.x, b4.z, acc[0][2]);
      acc[0][3] = fmaf(a4.x, b4.w, acc[0][3]);
      acc[1][0] = fmaf(a4.y, b4.x, acc[1][0]);
      acc[1][1] = fmaf(a4.y, b4.y, acc[1][1]);
      acc[1][2] = fmaf(a4.y, b4.z, acc[1][2]);
      acc[1][3] = fmaf(a4.y, b4.w, acc[1][3]);
      acc[2][0] = fmaf(a4.z, b4.x, acc[2][0]);
      acc[2][1] = fmaf(a4.z, b4.y, acc[2][1]);
      acc[2][2] = fmaf(a4.z, b4.z, acc[2][2]);
      acc[2][3] = fmaf(a4.z, b4.w, acc[2][3]);
      acc[3][0] = fmaf(a4.w, b4.x, acc[3][0]);
      acc[3][1] = fmaf(a4.w, b4.y, acc[3][1]);
      acc[3][2] = fmaf(a4.w, b4.z, acc[3][2]);
      acc[3][3] = fmaf(a4.w, b4.w, acc[3][3]);
    }
  }
#pragma unroll
  for (int i = 0; i < 4; ++i) {
    float4 cv = make_float4(acc[i][0], acc[i][1], acc[i][2], acc[i][3]);
    *(float4*)(C + (size_t)(m0 + ty * 4 + i) * Nd + n0 + tx * 4) = cv;
  }
}

// ---------------- RoPE in-place on the q and k parts of qkv -----------------
// qkv layout: [b*S+s][ q(1024) | k(1024) | v(1024) ], within each part h*64+dk
__global__ void rope_apply_kernel(float* __restrict__ qkv,
                                  const float* __restrict__ ct,
                                  const float* __restrict__ st) {
  int tid = blockIdx.x * blockDim.x + threadIdx.x;  // M_*1024 threads (one per pair)
  int i    = tid & 31;          // freq index
  int h    = (tid >> 5) & 15;
  int part = (tid >> 9) & 1;    // 0=q, 1=k
  int row  = tid >> 10;         // b*S+s
  int s    = row & (S_ - 1);
  float c  = ct[s * 32 + i];
  float sn = st[s * 32 + i];
  float* p = qkv + (size_t)row * NQKV + part * 1024 + h * 64 + i * 2;
  float2 v = *(float2*)p;
  float2 r;
  r.x = v.x * c - v.y * sn;   // x0*cos - x1*sin
  r.y = v.y * c + v.x * sn;   // x1*cos + x0*sin
  *(float2*)p = r;
}

// ---------------- flash-style causal attention ------------------------------
// One block = 128 q-rows of one (b,h). K/V staged in LDS 64 rows at a time.
// q row + o accumulator in registers; online softmax in 16-wide chunks.
__global__ __launch_bounds__(128) void attn_kernel(const float* __restrict__ qkv,
                                                   float* __restrict__ att) {
  __shared__ float Ks[64][64];
  __shared__ float Vs[64][64];
  const int tid = threadIdx.x;
  const int q0  = blockIdx.x * 128;
  const int h   = blockIdx.y;
  const int b   = blockIdx.z;
  const int q   = q0 + tid;

  const float* qrow = qkv + (size_t)(b * S_ + q) * NQKV + h * 64;
  float qr[64], o[64];
#pragma unroll
  for (int d4 = 0; d4 < 16; ++d4) {
    float4 v = *(const float4*)(qrow + d4 * 4);
    qr[d4 * 4 + 0] = v.x; qr[d4 * 4 + 1] = v.y;
    qr[d4 * 4 + 2] = v.z; qr[d4 * 4 + 3] = v.w;
  }
#pragma unroll
  for (int d = 0; d < 64; ++d) o[d] = 0.f;
  float mrun = -INFINITY, lrun = 0.f;

  const int ntiles = q0 / 64 + 2;   // covers k <= q0+127
  for (int kt = 0; kt < ntiles; ++kt) {
    const int k0 = kt * 64;
    const float* kbase = qkv + (size_t)(b * S_ + k0) * NQKV + 1024 + h * 64;
    __syncthreads();
#pragma unroll
    for (int m2 = 0; m2 < 8; ++m2) {
      int fid = m2 * 128 + tid;
      int r = fid >> 4;
      int c = (fid & 15) * 4;
      *(float4*)&Ks[r][c] = *(const float4*)(kbase + (size_t)r * NQKV + c);
      *(float4*)&Vs[r][c] = *(const float4*)(kbase + (size_t)r * NQKV + 1024 + c);
    }
    __syncthreads();
    if (k0 > q) continue;   // still hits the loop-top barrier next iter

#pragma unroll 1
    for (int c0 = 0; c0 < 64; c0 += 16) {
      if (k0 + c0 > q) break;
      float sc[16];
#pragma unroll
      for (int jj = 0; jj < 16; ++jj) {
        float dot = 0.f;
#pragma unroll
        for (int d4 = 0; d4 < 16; ++d4) {
          float4 kv = *(const float4*)&Ks[c0 + jj][d4 * 4];   // LDS broadcast
          dot = fmaf(qr[d4 * 4 + 0], kv.x, dot);
          dot = fmaf(qr[d4 * 4 + 1], kv.y, dot);
          dot = fmaf(qr[d4 * 4 + 2], kv.z, dot);
          dot = fmaf(qr[d4 * 4 + 3], kv.w, dot);
        }
        sc[jj] = (k0 + c0 + jj <= q) ? dot * 0.125f : -INFINITY;
      }
      float cmax = sc[0];
#pragma unroll
      for (int jj = 1; jj < 16; ++jj) cmax = fmaxf(cmax, sc[jj]);
      float mnew  = fmaxf(mrun, cmax);          // finite: jj=0 always valid here
      float scale = __expf(mrun - mnew);        // exp(-inf)=0 on first chunk
      lrun *= scale;
#pragma unroll
      for (int d = 0; d < 64; ++d) o[d] *= scale;
#pragma unroll
      for (int jj = 0; jj < 16; ++jj) {
        float e = __expf(sc[jj] - mnew);        // masked -> exp(-inf)=0
        lrun += e;
#pragma unroll
        for (int d4 = 0; d4 < 16; ++d4) {
          float4 vv = *(const float4*)&Vs[c0 + jj][d4 * 4];   // LDS broadcast
          o[d4 * 4 + 0] = fmaf(e, vv.x, o[d4 * 4 + 0]);
          o[d4 * 4 + 1] = fmaf(e, vv.y, o[d4 * 4 + 1]);
          o[d4 * 4 + 2] = fmaf(e, vv.z, o[d4 * 4 + 2]);
          o[d4 * 4 + 3] = fmaf(e, vv.w, o[d4 * 4 + 3]);
        }
      }
      mrun = mnew;
    }
  }

  const float inv = 1.f / lrun;
  float* orow = att + (size_t)(b * S_ + q) * 1024 + h * 64;
#pragma unroll
  for (int d4 = 0; d4 < 16; ++d4) {
    float4 ov = make_float4(o[d4 * 4 + 0] * inv, o[d4 * 4 + 1] * inv,
                            o[d4 * 4 + 2] * inv, o[d4 * 4 + 3] * inv);
    *(float4*)(orow + d4 * 4) = ov;
  }
}

// ---------------------------------------------------------------------------
extern "C" void kernel_launch(void* const* d_in, const int* in_sizes, int n_in,
                              void* d_out, int out_size, void* d_ws, size_t ws_size,
                              hipStream_t stream) {
  (void)in_sizes; (void)n_in; (void)out_size; (void)ws_size;
  const float* x   = (const float*)d_in[0];
  const int*   pos = (const int*)d_in[1];
  const float* w   = (const float*)d_in[2];   // (3,H,DK,D) row-major, D contiguous
  const float* wo  = (const float*)d_in[3];   // (D, H*DK) row-major
  float* out = (float*)d_out;

  // workspace layout (floats): qkv[M_*3072] | att[M_*1024] | ct[S*32] | st[S*32]
  float* qkv = (float*)d_ws;
  float* att = qkv + (size_t)M_ * NQKV;
  float* ct  = att + (size_t)M_ * 1024;
  float* st  = ct + S_ * 32;

  rope_table_kernel<<<(S_ * 32) / 256, 256, 0, stream>>>(pos, ct, st);

  dim3 gthr(16, 16);
  // qkv[b*S+s][qq*1024 + h*64 + dk] = sum_d x * weight
  gemm_nt_f32<<<dim3(NQKV / 64, M_ / 64), gthr, 0, stream>>>(x, w, qkv, M_, NQKV, D_);

  rope_apply_kernel<<<(M_ * 1024) / 256, 256, 0, stream>>>(qkv, ct, st);

  attn_kernel<<<dim3(S_ / 128, H_, B_), 128, 0, stream>>>(qkv, att);

  // out[b*S+s][o] = sum_i att * wo
  gemm_nt_f32<<<dim3(D_ / 64, M_ / 64), gthr, 0, stream>>>(att, wo, out, M_, D_, D_);
}

// Round 2
// 416.856 us; speedup vs baseline: 3.8633x; 3.8633x over previous
//
#include <hip/hip_runtime.h>
#include <hip/hip_bf16.h>
#include <math.h>

#define B_   2
#define S_   2048
#define D_   1024
#define H_   16
#define DK_  64
#define NQKV 3072
#define M_   (B_ * S_)

typedef unsigned short u16;
typedef unsigned int   u32;
typedef __attribute__((ext_vector_type(8))) short short8;   // 8 bf16 = 4 VGPR (MFMA A/B frag)
typedef __attribute__((ext_vector_type(4))) float f32x4;    // MFMA C/D frag
typedef __attribute__((ext_vector_type(4))) u16   u16x4;

__device__ __forceinline__ u16 f2bf(float f) {
  union { float f; u32 u; } v; v.f = f;
  u32 r = v.u + 0x7FFF + ((v.u >> 16) & 1);   // RN-even
  return (u16)(r >> 16);
}
__device__ __forceinline__ float bf2f(u16 h) {
  union { u32 u; float f; } v; v.u = ((u32)h) << 16;
  return v.f;
}

// ---------------- RoPE cos/sin table ----------------------------------------
__global__ void rope_table_kernel(const int* __restrict__ pos,
                                  float* __restrict__ ct,
                                  float* __restrict__ st) {
  int idx = blockIdx.x * blockDim.x + threadIdx.x;   // S*32
  int i = idx & 31;
  int s = idx >> 5;
  if (s >= S_) return;
  double p = (double)pos[s];
  double t = p * pow(10000.0, -(double)i / 32.0);
  ct[idx] = (float)cos(t);
  st[idx] = (float)sin(t);
}

// ---------------- f32 -> bf16 bulk convert ----------------------------------
__global__ void cvt_f32_bf16(const float* __restrict__ in, u16* __restrict__ out, int n4) {
  int i = blockIdx.x * 256 + threadIdx.x;
  if (i >= n4) return;
  float4 v = ((const float4*)in)[i];
  u16x4 o;
  o[0] = f2bf(v.x); o[1] = f2bf(v.y); o[2] = f2bf(v.z); o[3] = f2bf(v.w);
  ((u16x4*)out)[i] = o;
}

// ---------------- bf16 MFMA GEMM: C[M][N] = A[M][K] * Bm[N][K]^T ------------
// 128x128 tile, BK=64, 256 threads (4 waves 2x2), 4x4 16x16 frags per wave.
// LDS: row-major [128][64] bf16 (128B rows), 16B slots XOR-swizzled by (row&7).
template<bool OUT_BF16>
__global__ __launch_bounds__(256) void gemm_nt_mfma(const u16* __restrict__ A,
                                                    const u16* __restrict__ Bm,
                                                    void* __restrict__ Cout,
                                                    int Nd, int Kd) {
  __shared__ u16 As[128 * 64];
  __shared__ u16 Bs[128 * 64];
  const int t  = threadIdx.x;
  const int w  = t >> 6, l = t & 63;
  const int g  = l >> 4, ln = l & 15;
  const int wm = w >> 1, wn = w & 1;
  const int m0 = blockIdx.y * 128, n0 = blockIdx.x * 128;

  const f32x4 vzero = {0.f, 0.f, 0.f, 0.f};
  f32x4 acc[4][4];
#pragma unroll
  for (int i = 0; i < 4; ++i)
#pragma unroll
    for (int j = 0; j < 4; ++j) acc[i][j] = vzero;

  for (int k0 = 0; k0 < Kd; k0 += 64) {
    uint4 va[4], vb[4];
#pragma unroll
    for (int p = 0; p < 4; ++p) {
      int flat = p * 256 + t;
      int r = flat >> 3, s = flat & 7;
      va[p] = *(const uint4*)(A  + (size_t)(m0 + r) * Kd + k0 + s * 8);
      vb[p] = *(const uint4*)(Bm + (size_t)(n0 + r) * Kd + k0 + s * 8);
    }
    __syncthreads();   // previous iteration's frag reads complete
#pragma unroll
    for (int p = 0; p < 4; ++p) {
      int flat = p * 256 + t;
      int r = flat >> 3, s = flat & 7;
      int ss = (s ^ (r & 7)) * 8;
      *(uint4*)&As[r * 64 + ss] = va[p];
      *(uint4*)&Bs[r * 64 + ss] = vb[p];
    }
    __syncthreads();

#pragma unroll
    for (int ks = 0; ks < 2; ++ks) {
      short8 af[4], bf[4];
#pragma unroll
      for (int i = 0; i < 4; ++i) {
        int ra = wm * 64 + i * 16 + ln;
        af[i] = *(const short8*)&As[ra * 64 + (((ks * 4 + g) ^ (ra & 7)) * 8)];
        int rb = wn * 64 + i * 16 + ln;
        bf[i] = *(const short8*)&Bs[rb * 64 + (((ks * 4 + g) ^ (rb & 7)) * 8)];
      }
#pragma unroll
      for (int i = 0; i < 4; ++i)
#pragma unroll
        for (int j = 0; j < 4; ++j)
          acc[i][j] = __builtin_amdgcn_mfma_f32_16x16x32_bf16(af[i], bf[j], acc[i][j], 0, 0, 0);
    }
  }

  // epilogue: D row = wm*64+i*16+g*4+r, col = wn*64+j*16+ln
#pragma unroll
  for (int i = 0; i < 4; ++i)
#pragma unroll
    for (int j = 0; j < 4; ++j)
#pragma unroll
      for (int r = 0; r < 4; ++r) {
        size_t row = (size_t)(m0 + wm * 64 + i * 16 + g * 4 + r);
        size_t col = (size_t)(n0 + wn * 64 + j * 16 + ln);
        if (OUT_BF16) ((u16*)Cout)[row * Nd + col] = f2bf(acc[i][j][r]);
        else          ((float*)Cout)[row * Nd + col] = acc[i][j][r];
      }
}

// ---------------- RoPE in place on q,k parts of bf16 qkv --------------------
__global__ void rope_bf16_kernel(u16* __restrict__ qkvb,
                                 const float* __restrict__ ct,
                                 const float* __restrict__ st) {
  int tid = blockIdx.x * 256 + threadIdx.x;   // M_*1024 threads (one per pair)
  int i    = tid & 31;
  int h    = (tid >> 5) & 15;
  int part = (tid >> 9) & 1;
  int row  = tid >> 10;
  int s    = row & (S_ - 1);
  float c  = ct[s * 32 + i];
  float sn = st[s * 32 + i];
  u16* p = qkvb + (size_t)row * NQKV + part * 1024 + h * 64 + i * 2;
  u32 v = *(u32*)p;
  float x0 = bf2f((u16)(v & 0xffff));
  float x1 = bf2f((u16)(v >> 16));
  float r0 = x0 * c - x1 * sn;
  float r1 = x1 * c + x0 * sn;
  *(u32*)p = (u32)f2bf(r0) | ((u32)f2bf(r1) << 16);
}

// ---------------- V transpose: qkv v-part -> Vt[b][h][dk][s] ----------------
__global__ __launch_bounds__(256) void v_transpose_kernel(const u16* __restrict__ qkvb,
                                                          u16* __restrict__ Vt) {
  __shared__ u16 tile[64][72];
  const int t = threadIdx.x;
  const int s0 = blockIdx.x * 64, h = blockIdx.y, b = blockIdx.z;
  {
    int r = t >> 2, cs = (t & 3) * 16;
    const u16* src = qkvb + (size_t)(b * S_ + s0 + r) * NQKV + 2048 + h * 64 + cs;
    u16 v[16];
    *(uint4*)&v[0] = *(const uint4*)src;
    *(uint4*)&v[8] = *(const uint4*)(src + 8);
#pragma unroll
    for (int j = 0; j < 16; ++j) tile[cs + j][r] = v[j];
  }
  __syncthreads();
  {
    int d = t >> 2, ss = (t & 3) * 16;
    u16 o[16];
#pragma unroll
    for (int j = 0; j < 16; ++j) o[j] = tile[d][ss + j];
    u16* dst = Vt + ((size_t)(b * H_ + h) * 64 + d) * S_ + s0 + ss;
    *(uint4*)&dst[0] = *(uint4*)&o[0];
    *(uint4*)&dst[8] = *(uint4*)&o[8];
  }
}

// ---------------- flash attention, bf16 MFMA --------------------------------
// Block: 64 q rows of one (b,h); 4 waves x 16q. KV tiles of 64.
// QK^T swapped (A=K,B=Q -> D[key][q]) so softmax stats are lane-local per q.
__global__ __launch_bounds__(256) void attn_mfma(const u16* __restrict__ qkvb,
                                                 const u16* __restrict__ Vt,
                                                 u16* __restrict__ attb) {
  __shared__ u16 Ks[64 * 64];      // [key][dk] swizzled
  __shared__ u16 Vs[64 * 64];      // [dk][key] swizzled
  __shared__ u16 Ps[4][16 * 64];   // per-wave P [q][key] swizzled
  const int t = threadIdx.x;
  const int w = t >> 6, l = t & 63;
  const int g = l >> 4, ln = l & 15;
  const int q0 = blockIdx.x * 64;
  const int h = blockIdx.y, b = blockIdx.z;
  const int qg = q0 + w * 16 + ln;          // this lane's q row (softmax side)

  short8 qf[2];
  {
    const u16* qrow = qkvb + (size_t)(b * S_ + q0 + w * 16 + ln) * NQKV + h * 64;
    qf[0] = *(const short8*)(qrow + g * 8);
    qf[1] = *(const short8*)(qrow + 32 + g * 8);
  }

  const f32x4 vzero = {0.f, 0.f, 0.f, 0.f};
  f32x4 o[4];
#pragma unroll
  for (int dt = 0; dt < 4; ++dt) o[dt] = vzero;
  float mrun = -INFINITY, lrun = 0.f;

  const int nt = q0 / 64 + 1;
  for (int kt = 0; kt < nt; ++kt) {
    const int k0 = kt * 64;
    uint4 kv[2], vv[2];
#pragma unroll
    for (int p = 0; p < 2; ++p) {
      int flat = p * 256 + t, r = flat >> 3, s = flat & 7;
      kv[p] = *(const uint4*)(qkvb + (size_t)(b * S_ + k0 + r) * NQKV + D_ + h * 64 + s * 8);
      vv[p] = *(const uint4*)(Vt + ((size_t)(b * H_ + h) * 64 + r) * S_ + k0 + s * 8);
    }
    __syncthreads();
#pragma unroll
    for (int p = 0; p < 2; ++p) {
      int flat = p * 256 + t, r = flat >> 3, s = flat & 7;
      int ss = (s ^ (r & 7)) * 8;
      *(uint4*)&Ks[r * 64 + ss] = kv[p];
      *(uint4*)&Vs[r * 64 + ss] = vv[p];
    }
    __syncthreads();

    // QK^T: D[key][q]
    f32x4 sacc[4];
#pragma unroll
    for (int st = 0; st < 4; ++st) sacc[st] = vzero;
#pragma unroll
    for (int st = 0; st < 4; ++st) {
      const int kr = st * 16 + ln;
#pragma unroll
      for (int ks = 0; ks < 2; ++ks) {
        short8 kf = *(const short8*)&Ks[kr * 64 + (((ks * 4 + g) ^ (kr & 7)) * 8)];
        sacc[st] = __builtin_amdgcn_mfma_f32_16x16x32_bf16(kf, qf[ks], sacc[st], 0, 0, 0);
      }
    }

    // mask + online softmax (lane owns q = qg; in-lane keys st*16+g*4+r)
    float tmax = -INFINITY;
#pragma unroll
    for (int st = 0; st < 4; ++st)
#pragma unroll
      for (int r = 0; r < 4; ++r) {
        int key = k0 + st * 16 + g * 4 + r;
        float sv = sacc[st][r] * 0.125f;
        sv = (key <= qg) ? sv : -INFINITY;
        sacc[st][r] = sv;
        tmax = fmaxf(tmax, sv);
      }
    tmax = fmaxf(tmax, __shfl_xor(tmax, 16));
    tmax = fmaxf(tmax, __shfl_xor(tmax, 32));
    float mnew = fmaxf(mrun, tmax);
    float al = __expf(mrun - mnew);
    float lsum = 0.f;
#pragma unroll
    for (int st = 0; st < 4; ++st) {
      u16x4 pk;
#pragma unroll
      for (int r = 0; r < 4; ++r) {
        float pe = __expf(sacc[st][r] - mnew);
        lsum += pe;
        pk[r] = f2bf(pe);
      }
      *(u16x4*)&Ps[w][ln * 64 + ((st * 16 + g * 4) ^ ((ln & 7) << 3))] = pk;
    }
    lsum += __shfl_xor(lsum, 16);
    lsum += __shfl_xor(lsum, 32);
    lrun = lrun * al + lsum;
    mrun = mnew;

    // rescale o (o rows are q = g*4+r; scale lives in lane g*4+r)
#pragma unroll
    for (int r = 0; r < 4; ++r) {
      float sr = __shfl(al, g * 4 + r);
#pragma unroll
      for (int dt = 0; dt < 4; ++dt) o[dt][r] *= sr;
    }

    // PV: D[q][dk]
#pragma unroll
    for (int ks = 0; ks < 2; ++ks) {
      short8 pf = *(const short8*)&Ps[w][ln * 64 + (((ks * 4 + g) ^ (ln & 7)) * 8)];
#pragma unroll
      for (int dt = 0; dt < 4; ++dt) {
        const int dr = dt * 16 + ln;
        short8 vf = *(const short8*)&Vs[dr * 64 + (((ks * 4 + g) ^ (dr & 7)) * 8)];
        o[dt] = __builtin_amdgcn_mfma_f32_16x16x32_bf16(pf, vf, o[dt], 0, 0, 0);
      }
    }
  }

  float linv = 1.f / lrun;
#pragma unroll
  for (int r = 0; r < 4; ++r) {
    float ir = __shfl(linv, g * 4 + r);
    size_t row = (size_t)(b * S_ + q0 + w * 16 + g * 4 + r);
#pragma unroll
    for (int dt = 0; dt < 4; ++dt)
      attb[row * D_ + h * 64 + dt * 16 + ln] = f2bf(o[dt][r] * ir);
  }
}

// ---------------------------------------------------------------------------
extern "C" void kernel_launch(void* const* d_in, const int* in_sizes, int n_in,
                              void* d_out, int out_size, void* d_ws, size_t ws_size,
                              hipStream_t stream) {
  (void)in_sizes; (void)n_in; (void)out_size; (void)ws_size;
  const float* x   = (const float*)d_in[0];
  const int*   pos = (const int*)d_in[1];
  const float* w   = (const float*)d_in[2];   // (3,H,DK,D)
  const float* wo  = (const float*)d_in[3];   // (D, H*DK)
  float* out = (float*)d_out;

  // ws layout (u16 elements unless noted): ~59.2 MB total
  u16* qkvb = (u16*)d_ws;            // [4096][3072]
  u16* Vt   = qkvb + (size_t)M_ * NQKV;          // [2][16][64][2048]
  u16* attb = Vt + (size_t)B_ * H_ * 64 * S_;    // [4096][1024]
  u16* xb   = attb + (size_t)M_ * D_;            // [4096][1024]
  u16* wb   = xb + (size_t)M_ * D_;              // [3072][1024]
  u16* wob  = wb + (size_t)NQKV * D_;            // [1024][1024]
  float* ct = (float*)(wob + (size_t)D_ * D_);
  float* st = ct + S_ * 32;

  rope_table_kernel<<<(S_ * 32) / 256, 256, 0, stream>>>(pos, ct, st);

  cvt_f32_bf16<<<(M_ * D_ / 4) / 256, 256, 0, stream>>>(x, xb, M_ * D_ / 4);
  cvt_f32_bf16<<<(NQKV * D_ / 4) / 256, 256, 0, stream>>>(w, wb, NQKV * D_ / 4);
  cvt_f32_bf16<<<(D_ * D_ / 4) / 256, 256, 0, stream>>>(wo, wob, D_ * D_ / 4);

  gemm_nt_mfma<true><<<dim3(NQKV / 128, M_ / 128), 256, 0, stream>>>(xb, wb, qkvb, NQKV, D_);

  rope_bf16_kernel<<<(M_ * 1024) / 256, 256, 0, stream>>>(qkvb, ct, st);
  v_transpose_kernel<<<dim3(S_ / 64, H_, B_), 256, 0, stream>>>(qkvb, Vt);

  attn_mfma<<<dim3(S_ / 64, H_, B_), 256, 0, stream>>>(qkvb, Vt, attb);

  gemm_nt_mfma<false><<<dim3(D_ / 128, M_ / 128), 256, 0, stream>>>(attb, wob, out, D_, D_);
}

// Round 3
// 211.430 us; speedup vs baseline: 7.6169x; 1.9716x over previous
//
#include <hip/hip_runtime.h>
#include <hip/hip_bf16.h>
#include <math.h>

#define B_   2
#define S_   2048
#define D_   1024
#define H_   16
#define DK_  64
#define NQKV 3072
#define M_   (B_ * S_)

typedef unsigned short u16;
typedef unsigned int   u32;
typedef __attribute__((ext_vector_type(8))) short short8;   // 8 bf16 (MFMA A/B frag)
typedef __attribute__((ext_vector_type(4))) float f32x4;    // MFMA C/D frag
typedef __attribute__((ext_vector_type(4))) u16   u16x4;

typedef const __attribute__((address_space(1))) void* gvptr;
typedef __attribute__((address_space(3))) void* lvptr;

__device__ __forceinline__ u16 f2bf(float f) {
  union { float f; u32 u; } v; v.f = f;
  u32 r = v.u + 0x7FFF + ((v.u >> 16) & 1);   // RN-even
  return (u16)(r >> 16);
}
__device__ __forceinline__ float bf2f(u16 h) {
  union { u32 u; float f; } v; v.u = ((u32)h) << 16;
  return v.f;
}

#define MEMFENCE() asm volatile("" ::: "memory")
#define RAW_BARRIER() do { MEMFENCE(); __builtin_amdgcn_s_barrier(); MEMFENCE(); } while (0)

// ---------------- RoPE cos/sin table ----------------------------------------
__global__ void rope_table_kernel(const int* __restrict__ pos,
                                  float* __restrict__ ct,
                                  float* __restrict__ st) {
  int idx = blockIdx.x * blockDim.x + threadIdx.x;   // S*32
  int i = idx & 31;
  int s = idx >> 5;
  if (s >= S_) return;
  double p = (double)pos[s];
  double t = p * pow(10000.0, -(double)i / 32.0);
  ct[idx] = (float)cos(t);
  st[idx] = (float)sin(t);
}

// ---------------- f32 -> bf16 bulk convert ----------------------------------
__global__ void cvt_f32_bf16(const float* __restrict__ in, u16* __restrict__ out, int n4) {
  int i = blockIdx.x * 256 + threadIdx.x;
  if (i >= n4) return;
  float4 v = ((const float4*)in)[i];
  u16x4 o;
  o[0] = f2bf(v.x); o[1] = f2bf(v.y); o[2] = f2bf(v.z); o[3] = f2bf(v.w);
  ((u16x4*)out)[i] = o;
}

// ---------------- bf16 MFMA GEMM (m97 structure) ----------------------------
// C[M][N] = A[M][K] * Bm[N][K]^T.  128x128 tile, BK=64, 4 waves 2x2, 4x4 frags.
// Staging: global_load_lds 16B, linear LDS dest, inverse-swizzled SOURCE,
// XOR-swizzled ds_read (rule #21 both-sides-or-neither).
template<bool OUT_BF16>
__global__ __launch_bounds__(256) void gemm_nt_mfma(const u16* __restrict__ A,
                                                    const u16* __restrict__ Bm,
                                                    void* __restrict__ Cout,
                                                    int Nd, int Kd) {
  __shared__ u16 As[128 * 64];
  __shared__ u16 Bs[128 * 64];
  const int t  = threadIdx.x;
  const int w  = t >> 6, l = t & 63;
  const int g  = l >> 4, ln = l & 15;
  const int wm = w >> 1, wn = w & 1;
  const int m0 = blockIdx.y * 128, n0 = blockIdx.x * 128;

  const f32x4 vzero = {0.f, 0.f, 0.f, 0.f};
  f32x4 acc[4][4];
#pragma unroll
  for (int i = 0; i < 4; ++i)
#pragma unroll
    for (int j = 0; j < 4; ++j) acc[i][j] = vzero;

  for (int k0 = 0; k0 < Kd; k0 += 64) {
    __syncthreads();   // previous iteration's frag reads complete
#pragma unroll
    for (int p = 0; p < 4; ++p) {
      int c = p * 256 + t;
      int r = c >> 3, sx = (c & 7) ^ (r & 7);
      __builtin_amdgcn_global_load_lds(
          (gvptr)(A + (size_t)(m0 + r) * Kd + k0 + sx * 8),
          (lvptr)(&As[(p * 256 + w * 64) * 8]), 16, 0, 0);
      __builtin_amdgcn_global_load_lds(
          (gvptr)(Bm + (size_t)(n0 + r) * Kd + k0 + sx * 8),
          (lvptr)(&Bs[(p * 256 + w * 64) * 8]), 16, 0, 0);
    }
    __syncthreads();   // drains vmcnt(0): LDS ready

#pragma unroll
    for (int ks = 0; ks < 2; ++ks) {
      short8 af[4], bf[4];
#pragma unroll
      for (int i = 0; i < 4; ++i) {
        int ra = wm * 64 + i * 16 + ln;
        af[i] = *(const short8*)&As[ra * 64 + (((ks * 4 + g) ^ (ra & 7)) * 8)];
        int rb = wn * 64 + i * 16 + ln;
        bf[i] = *(const short8*)&Bs[rb * 64 + (((ks * 4 + g) ^ (rb & 7)) * 8)];
      }
#pragma unroll
      for (int i = 0; i < 4; ++i)
#pragma unroll
        for (int j = 0; j < 4; ++j)
          acc[i][j] = __builtin_amdgcn_mfma_f32_16x16x32_bf16(af[i], bf[j], acc[i][j], 0, 0, 0);
    }
  }

  // epilogue: D row = wm*64+i*16+g*4+r, col = wn*64+j*16+ln
#pragma unroll
  for (int i = 0; i < 4; ++i)
#pragma unroll
    for (int j = 0; j < 4; ++j)
#pragma unroll
      for (int r = 0; r < 4; ++r) {
        size_t row = (size_t)(m0 + wm * 64 + i * 16 + g * 4 + r);
        size_t col = (size_t)(n0 + wn * 64 + j * 16 + ln);
        if (OUT_BF16) ((u16*)Cout)[row * Nd + col] = f2bf(acc[i][j][r]);
        else          ((float*)Cout)[row * Nd + col] = acc[i][j][r];
      }
}

// ---------------- RoPE in place, 16B per thread -----------------------------
__global__ void rope_bf16_kernel(u16* __restrict__ qkvb,
                                 const float* __restrict__ ct,
                                 const float* __restrict__ st) {
  int tid = blockIdx.x * 256 + threadIdx.x;   // M_*256 threads, 4 pairs each
  int p4   = (tid & 7) * 4;        // pair base index (0..28)
  int h    = (tid >> 3) & 15;
  int part = (tid >> 7) & 1;
  int row  = tid >> 8;
  int s    = row & (S_ - 1);
  float4 c4 = *(const float4*)&ct[s * 32 + p4];
  float4 s4 = *(const float4*)&st[s * 32 + p4];
  u16* p = qkvb + (size_t)row * NQKV + part * 1024 + h * 64 + p4 * 2;
  u16 v[8];
  *(uint4*)v = *(const uint4*)p;
  float x0, x1;
  x0 = bf2f(v[0]); x1 = bf2f(v[1]);
  v[0] = f2bf(x0 * c4.x - x1 * s4.x); v[1] = f2bf(x1 * c4.x + x0 * s4.x);
  x0 = bf2f(v[2]); x1 = bf2f(v[3]);
  v[2] = f2bf(x0 * c4.y - x1 * s4.y); v[3] = f2bf(x1 * c4.y + x0 * s4.y);
  x0 = bf2f(v[4]); x1 = bf2f(v[5]);
  v[4] = f2bf(x0 * c4.z - x1 * s4.z); v[5] = f2bf(x1 * c4.z + x0 * s4.z);
  x0 = bf2f(v[6]); x1 = bf2f(v[7]);
  v[6] = f2bf(x0 * c4.w - x1 * s4.w); v[7] = f2bf(x1 * c4.w + x0 * s4.w);
  *(uint4*)p = *(uint4*)v;
}

// ---------------- V transpose: qkv v-part -> Vt[b][h][dk][s] ----------------
__global__ __launch_bounds__(256) void v_transpose_kernel(const u16* __restrict__ qkvb,
                                                          u16* __restrict__ Vt) {
  __shared__ u16 tile[64][72];
  const int t = threadIdx.x;
  const int s0 = blockIdx.x * 64, h = blockIdx.y, b = blockIdx.z;
  {
    int r = t >> 2, cs = (t & 3) * 16;
    const u16* src = qkvb + (size_t)(b * S_ + s0 + r) * NQKV + 2048 + h * 64 + cs;
    u16 v[16];
    *(uint4*)&v[0] = *(const uint4*)src;
    *(uint4*)&v[8] = *(const uint4*)(src + 8);
#pragma unroll
    for (int j = 0; j < 16; ++j) tile[cs + j][r] = v[j];
  }
  __syncthreads();
  {
    int d = t >> 2, ss = (t & 3) * 16;
    u16 o[16];
#pragma unroll
    for (int j = 0; j < 16; ++j) o[j] = tile[d][ss + j];
    u16* dst = Vt + ((size_t)(b * H_ + h) * 64 + d) * S_ + s0 + ss;
    *(uint4*)&dst[0] = *(uint4*)&o[0];
    *(uint4*)&dst[8] = *(uint4*)&o[8];
  }
}

// ---------------- flash attention, bf16 MFMA, paired q-tiles ----------------
// Block = q-tiles {31-bx, bx} of one (b,h): uniform 33 KV-tiles of work.
// K/V double-buffered in LDS via global_load_lds; raw barriers + counted
// vmcnt so next-tile loads stay in flight across barriers (never drain to 0
// in steady state). 4 waves x 16 q-rows. Diagonal-tile-only masking,
// defer-max rescale skip, setprio around MFMA clusters.
__global__ __launch_bounds__(256) void attn_mfma(const u16* __restrict__ qkvb,
                                                 const u16* __restrict__ Vt,
                                                 u16* __restrict__ attb) {
  __shared__ u16 Ks[2][64 * 64];   // [key][dk], source-swizzled
  __shared__ u16 Vs[2][64 * 64];   // [dk][key], source-swizzled
  __shared__ u16 Ps[4][16 * 64];   // per-wave P [q][key], swizzled
  const int t = threadIdx.x;
  const int w = t >> 6, l = t & 63;
  const int g = l >> 4, ln = l & 15;
  const int h = blockIdx.y, b = blockIdx.z;
  const size_t bS = (size_t)b * S_;
  const u16* Kbase = qkvb + bS * NQKV + D_ + h * 64;          // row stride NQKV
  const u16* Vbase = Vt + (size_t)(b * H_ + h) * 64 * S_;     // row stride S_

  // stage one 64-key tile (K: [64][64] from qkvb, V: [64 dk][64 key] from Vt)
  // chunk c -> LDS slot (r=c>>3, s=c&7); source column slot s ^ (r&7).
  auto stage = [&](int buf, int k0) {
#pragma unroll
    for (int p = 0; p < 2; ++p) {
      int c = p * 256 + t;
      int r = c >> 3, sx = (c & 7) ^ (r & 7);
      __builtin_amdgcn_global_load_lds(
          (gvptr)(Kbase + (size_t)(k0 + r) * NQKV + sx * 8),
          (lvptr)(&Ks[buf][(p * 256 + w * 64) * 8]), 16, 0, 0);
      __builtin_amdgcn_global_load_lds(
          (gvptr)(Vbase + (size_t)r * S_ + k0 + sx * 8),
          (lvptr)(&Vs[buf][(p * 256 + w * 64) * 8]), 16, 0, 0);
    }
  };

  const f32x4 vzero = {0.f, 0.f, 0.f, 0.f};

#pragma unroll 1
  for (int half = 0; half < 2; ++half) {
    const int tq = (half == 0) ? (31 - blockIdx.x) : blockIdx.x;  // heavy first
    const int q0 = tq * 64;
    const int nt = tq + 1;
    const int qg = q0 + w * 16 + ln;

    short8 qf[2];
    {
      const u16* qrow = qkvb + (bS + q0 + w * 16 + ln) * NQKV + h * 64;
      qf[0] = *(const short8*)(qrow + g * 8);
      qf[1] = *(const short8*)(qrow + 32 + g * 8);
    }

    f32x4 o[4];
#pragma unroll
    for (int dt = 0; dt < 4; ++dt) o[dt] = vzero;
    float mrun = -INFINITY, lrun = 0.f;

    int cur = 0;
    stage(0, 0);                       // prologue (LDS free: post-barrier state)

#pragma unroll 1
    for (int kt = 0; kt < nt; ++kt) {
      const int k0 = kt * 64;
      if (kt + 1 < nt) {
        stage(cur ^ 1, k0 + 64);       // 4 loads/thread stay in flight
        asm volatile("s_waitcnt vmcnt(4)" ::: "memory");
      } else {
        asm volatile("s_waitcnt vmcnt(0)" ::: "memory");
      }
      RAW_BARRIER();                   // buf[cur] fully staged, all waves

      // ---- QK^T: D[key][q] (swapped operands) ----
      f32x4 sacc[4];
#pragma unroll
      for (int st = 0; st < 4; ++st) sacc[st] = vzero;
      __builtin_amdgcn_s_setprio(1);
#pragma unroll
      for (int st = 0; st < 4; ++st) {
        const int kr = st * 16 + ln;
#pragma unroll
        for (int ks = 0; ks < 2; ++ks) {
          short8 kf = *(const short8*)&Ks[cur][kr * 64 + (((ks * 4 + g) ^ (kr & 7)) * 8)];
          sacc[st] = __builtin_amdgcn_mfma_f32_16x16x32_bf16(kf, qf[ks], sacc[st], 0, 0, 0);
        }
      }
      __builtin_amdgcn_s_setprio(0);

      // ---- online softmax (lane owns q=qg; in-lane keys st*16+g*4+r) ----
      float tmax = -INFINITY;
      if (kt == nt - 1) {              // diagonal tile: causal mask
#pragma unroll
        for (int st = 0; st < 4; ++st)
#pragma unroll
          for (int r = 0; r < 4; ++r) {
            int key = k0 + st * 16 + g * 4 + r;
            float sv = sacc[st][r] * 0.125f;
            sv = (key <= qg) ? sv : -INFINITY;
            sacc[st][r] = sv;
            tmax = fmaxf(tmax, sv);
          }
      } else {                         // full tile: no mask
#pragma unroll
        for (int st = 0; st < 4; ++st)
#pragma unroll
          for (int r = 0; r < 4; ++r) {
            float sv = sacc[st][r] * 0.125f;
            sacc[st][r] = sv;
            tmax = fmaxf(tmax, sv);
          }
      }
      tmax = fmaxf(tmax, __shfl_xor(tmax, 16));
      tmax = fmaxf(tmax, __shfl_xor(tmax, 32));
      float mnew = fmaxf(mrun, tmax);
      float al = 1.f;
      if (!__all(tmax <= mrun)) {      // defer-max: skip rescale when max unchanged
        al = __expf(mrun - mnew);
#pragma unroll
        for (int r = 0; r < 4; ++r) {
          float sr = __shfl(al, g * 4 + r);
#pragma unroll
          for (int dt = 0; dt < 4; ++dt) o[dt][r] *= sr;
        }
      } else {
        mnew = mrun;
      }
      float lsum = 0.f;
#pragma unroll
      for (int st = 0; st < 4; ++st) {
        u16x4 pk;
#pragma unroll
        for (int r = 0; r < 4; ++r) {
          float pe = __expf(sacc[st][r] - mnew);
          lsum += pe;
          pk[r] = f2bf(pe);
        }
        *(u16x4*)&Ps[w][ln * 64 + ((st * 16 + g * 4) ^ ((ln & 7) << 3))] = pk;
      }
      lsum += __shfl_xor(lsum, 16);
      lsum += __shfl_xor(lsum, 32);
      lrun = lrun * al + lsum;
      mrun = mnew;

      // ---- PV: D[q][dk] ----
      __builtin_amdgcn_s_setprio(1);
#pragma unroll
      for (int ks = 0; ks < 2; ++ks) {
        short8 pf = *(const short8*)&Ps[w][ln * 64 + (((ks * 4 + g) ^ (ln & 7)) * 8)];
#pragma unroll
        for (int dt = 0; dt < 4; ++dt) {
          const int dr = dt * 16 + ln;
          short8 vf = *(const short8*)&Vs[cur][dr * 64 + (((ks * 4 + g) ^ (dr & 7)) * 8)];
          o[dt] = __builtin_amdgcn_mfma_f32_16x16x32_bf16(pf, vf, o[dt], 0, 0, 0);
        }
      }
      __builtin_amdgcn_s_setprio(0);

      asm volatile("s_waitcnt lgkmcnt(0)" ::: "memory");
      RAW_BARRIER();                   // release buf[cur] for restaging
      cur ^= 1;
    }

    // ---- epilogue ----
    float linv = 1.f / lrun;
#pragma unroll
    for (int r = 0; r < 4; ++r) {
      float ir = __shfl(linv, g * 4 + r);
      size_t row = bS + q0 + w * 16 + g * 4 + r;
#pragma unroll
      for (int dt = 0; dt < 4; ++dt)
        attb[row * D_ + h * 64 + dt * 16 + ln] = f2bf(o[dt][r] * ir);
    }
    asm volatile("s_waitcnt vmcnt(0)" ::: "memory");  // clean count for next half
  }
}

// ---------------------------------------------------------------------------
extern "C" void kernel_launch(void* const* d_in, const int* in_sizes, int n_in,
                              void* d_out, int out_size, void* d_ws, size_t ws_size,
                              hipStream_t stream) {
  (void)in_sizes; (void)n_in; (void)out_size; (void)ws_size;
  const float* x   = (const float*)d_in[0];
  const int*   pos = (const int*)d_in[1];
  const float* w   = (const float*)d_in[2];   // (3,H,DK,D)
  const float* wo  = (const float*)d_in[3];   // (D, H*DK)
  float* out = (float*)d_out;

  u16* qkvb = (u16*)d_ws;                        // [4096][3072]
  u16* Vt   = qkvb + (size_t)M_ * NQKV;          // [2][16][64][2048]
  u16* attb = Vt + (size_t)B_ * H_ * 64 * S_;    // [4096][1024]
  u16* xb   = attb + (size_t)M_ * D_;            // [4096][1024]
  u16* wb   = xb + (size_t)M_ * D_;              // [3072][1024]
  u16* wob  = wb + (size_t)NQKV * D_;            // [1024][1024]
  float* ct = (float*)(wob + (size_t)D_ * D_);
  float* st = ct + S_ * 32;

  rope_table_kernel<<<(S_ * 32) / 256, 256, 0, stream>>>(pos, ct, st);

  cvt_f32_bf16<<<(M_ * D_ / 4) / 256, 256, 0, stream>>>(x, xb, M_ * D_ / 4);
  cvt_f32_bf16<<<(NQKV * D_ / 4) / 256, 256, 0, stream>>>(w, wb, NQKV * D_ / 4);
  cvt_f32_bf16<<<(D_ * D_ / 4) / 256, 256, 0, stream>>>(wo, wob, D_ * D_ / 4);

  gemm_nt_mfma<true><<<dim3(NQKV / 128, M_ / 128), 256, 0, stream>>>(xb, wb, qkvb, NQKV, D_);

  rope_bf16_kernel<<<(M_ * 256) / 256, 256, 0, stream>>>(qkvb, ct, st);
  v_transpose_kernel<<<dim3(S_ / 64, H_, B_), 256, 0, stream>>>(qkvb, Vt);

  attn_mfma<<<dim3(16, H_, B_), 256, 0, stream>>>(qkvb, Vt, attb);

  gemm_nt_mfma<false><<<dim3(D_ / 128, M_ / 128), 256, 0, stream>>>(attb, wob, out, D_, D_);
}

// Round 4
// 208.128 us; speedup vs baseline: 7.7378x; 1.0159x over previous
//
#include <hip/hip_runtime.h>
#include <hip/hip_bf16.h>
#include <math.h>

#define B_   2
#define S_   2048
#define D_   1024
#define H_   16
#define DK_  64
#define NQKV 3072
#define M_   (B_ * S_)

typedef unsigned short u16;
typedef unsigned int   u32;
typedef __attribute__((ext_vector_type(8))) short short8;   // 8 bf16 (MFMA A/B frag)
typedef __attribute__((ext_vector_type(4))) float f32x4;    // MFMA C/D frag
typedef __attribute__((ext_vector_type(4))) u16   u16x4;

typedef const __attribute__((address_space(1))) void* gvptr;
typedef __attribute__((address_space(3))) void* lvptr;

// combined scale: 1/sqrt(64) * log2(e), so scores are in exp2 units directly
#define QSCALE 0.18033688011f

#if __has_builtin(__builtin_amdgcn_exp2f)
#define EXP2F(x) __builtin_amdgcn_exp2f(x)
#else
#define EXP2F(x) __expf(0.69314718056f * (x))
#endif

__device__ __forceinline__ u16 f2bf(float f) {
  union { float f; u32 u; } v; v.f = f;
  u32 r = v.u + 0x7FFF + ((v.u >> 16) & 1);   // RN-even
  return (u16)(r >> 16);
}
__device__ __forceinline__ float bf2f(u16 h) {
  union { u32 u; float f; } v; v.u = ((u32)h) << 16;
  return v.f;
}
__device__ __forceinline__ u32 cvtpk_bf16(float lo, float hi) {
  u32 r;
  asm("v_cvt_pk_bf16_f32 %0, %1, %2" : "=v"(r) : "v"(lo), "v"(hi));
  return r;
}

#define MEMFENCE() asm volatile("" ::: "memory")
#define RAW_BARRIER() do { MEMFENCE(); __builtin_amdgcn_s_barrier(); MEMFENCE(); } while (0)

// LDS row-swizzle: spreads both natural rows and attn's permuted QK rows
// across 8 distinct 16B slots (2-way max = free per m136)
#define SWZ(r) ((((r) & 7) ^ ((((r) >> 3) & 1) << 2)))

// ---------------- RoPE cos/sin table (float2 per (s, pair)) -----------------
__global__ void rope_cs_kernel(const int* __restrict__ pos,
                               float2* __restrict__ cs) {
  int idx = blockIdx.x * 256 + threadIdx.x;   // S*32
  int i = idx & 31;
  int s = idx >> 5;
  double p = (double)pos[s];
  double t = p * pow(10000.0, -(double)i / 32.0);
  cs[idx] = make_float2((float)cos(t), (float)sin(t));
}

// ---------------- merged f32 -> bf16 convert for x, w, wo -------------------
#define N4X (M_ * D_ / 4)       // 1048576
#define N4W (NQKV * D_ / 4)     //  786432
#define N4WO (D_ * D_ / 4)      //  262144
__global__ void cvt_all_kernel(const float* __restrict__ x,
                               const float* __restrict__ w,
                               const float* __restrict__ wo,
                               u16* __restrict__ dst) {
  int i = blockIdx.x * 256 + threadIdx.x;
  float4 v;
  if (i < N4X)            v = ((const float4*)x)[i];
  else if (i < N4X + N4W) v = ((const float4*)w)[i - N4X];
  else                    v = ((const float4*)wo)[i - (N4X + N4W)];
  u16x4 o;
  o[0] = f2bf(v.x); o[1] = f2bf(v.y); o[2] = f2bf(v.z); o[3] = f2bf(v.w);
  ((u16x4*)dst)[i] = o;
}

// ---------------- bf16 MFMA GEMM (m97 structure), optional fused RoPE -------
// C[M][N] = A[M][K] * Bm[N][K]^T. 128x128 tile, BK=64, 4 waves 2x2, 4x4 frags.
// Staging: global_load_lds 16B, linear LDS dest, inverse-swizzled SOURCE,
// XOR-swizzled ds_read (rule #21). ROPE: rotate q/k output pairs in epilogue.
template<bool OUT_BF16, bool ROPE>
__global__ __launch_bounds__(256) void gemm_nt_mfma(const u16* __restrict__ A,
                                                    const u16* __restrict__ Bm,
                                                    void* __restrict__ Cout,
                                                    const float2* __restrict__ cstab,
                                                    int Nd, int Kd) {
  __shared__ u16 As[128 * 64];
  __shared__ u16 Bs[128 * 64];
  const int t  = threadIdx.x;
  const int w  = t >> 6, l = t & 63;
  const int g  = l >> 4, ln = l & 15;
  const int wm = w >> 1, wn = w & 1;
  const int m0 = blockIdx.y * 128, n0 = blockIdx.x * 128;

  const f32x4 vzero = {0.f, 0.f, 0.f, 0.f};
  f32x4 acc[4][4];
#pragma unroll
  for (int i = 0; i < 4; ++i)
#pragma unroll
    for (int j = 0; j < 4; ++j) acc[i][j] = vzero;

  for (int k0 = 0; k0 < Kd; k0 += 64) {
    __syncthreads();
#pragma unroll
    for (int p = 0; p < 4; ++p) {
      int c = p * 256 + t;
      int r = c >> 3, sx = (c & 7) ^ (r & 7);
      __builtin_amdgcn_global_load_lds(
          (gvptr)(A + (size_t)(m0 + r) * Kd + k0 + sx * 8),
          (lvptr)(&As[(p * 256 + w * 64) * 8]), 16, 0, 0);
      __builtin_amdgcn_global_load_lds(
          (gvptr)(Bm + (size_t)(n0 + r) * Kd + k0 + sx * 8),
          (lvptr)(&Bs[(p * 256 + w * 64) * 8]), 16, 0, 0);
    }
    __syncthreads();

#pragma unroll
    for (int ks = 0; ks < 2; ++ks) {
      short8 af[4], bf[4];
#pragma unroll
      for (int i = 0; i < 4; ++i) {
        int ra = wm * 64 + i * 16 + ln;
        af[i] = *(const short8*)&As[ra * 64 + (((ks * 4 + g) ^ (ra & 7)) * 8)];
        int rb = wn * 64 + i * 16 + ln;
        bf[i] = *(const short8*)&Bs[rb * 64 + (((ks * 4 + g) ^ (rb & 7)) * 8)];
      }
#pragma unroll
      for (int i = 0; i < 4; ++i)
#pragma unroll
        for (int j = 0; j < 4; ++j)
          acc[i][j] = __builtin_amdgcn_mfma_f32_16x16x32_bf16(af[i], bf[j], acc[i][j], 0, 0, 0);
    }
  }

  // epilogue: D row = wm*64+i*16+g*4+r, col = wn*64+j*16+ln
  if (ROPE && n0 < 2048) {   // q or k block: rotate pairs (even/odd cols)
#pragma unroll
    for (int i = 0; i < 4; ++i)
#pragma unroll
      for (int r = 0; r < 4; ++r) {
        int rowi = m0 + wm * 64 + i * 16 + g * 4 + r;
        int srow = rowi & (S_ - 1);
#pragma unroll
        for (int j = 0; j < 4; ++j) {
          int dk = j * 16 + ln;
          float2 cs = cstab[srow * 32 + (dk >> 1)];
          float v = acc[i][j][r];
          float p = __shfl_xor(v, 1);
          float sn = (ln & 1) ? cs.y : -cs.y;
          float rot = fmaf(p, sn, v * cs.x);
          ((u16*)Cout)[(size_t)rowi * Nd + n0 + wn * 64 + j * 16 + ln] = f2bf(rot);
        }
      }
  } else {
#pragma unroll
    for (int i = 0; i < 4; ++i)
#pragma unroll
      for (int j = 0; j < 4; ++j)
#pragma unroll
        for (int r = 0; r < 4; ++r) {
          size_t row = (size_t)(m0 + wm * 64 + i * 16 + g * 4 + r);
          size_t col = (size_t)(n0 + wn * 64 + j * 16 + ln);
          if (OUT_BF16) ((u16*)Cout)[row * Nd + col] = f2bf(acc[i][j][r]);
          else          ((float*)Cout)[row * Nd + col] = acc[i][j][r];
        }
  }
}

// ---------------- V transpose: qkv v-part -> Vt[b][h][dk][s] ----------------
__global__ __launch_bounds__(256) void v_transpose_kernel(const u16* __restrict__ qkvb,
                                                          u16* __restrict__ Vt) {
  __shared__ u16 tile[64][72];
  const int t = threadIdx.x;
  const int s0 = blockIdx.x * 64, h = blockIdx.y, b = blockIdx.z;
  {
    int r = t >> 2, cs = (t & 3) * 16;
    const u16* src = qkvb + (size_t)(b * S_ + s0 + r) * NQKV + 2048 + h * 64 + cs;
    u16 v[16];
    *(uint4*)&v[0] = *(const uint4*)src;
    *(uint4*)&v[8] = *(const uint4*)(src + 8);
#pragma unroll
    for (int j = 0; j < 16; ++j) tile[cs + j][r] = v[j];
  }
  __syncthreads();
  {
    int d = t >> 2, ss = (t & 3) * 16;
    u16 o[16];
#pragma unroll
    for (int j = 0; j < 16; ++j) o[j] = tile[d][ss + j];
    u16* dst = Vt + ((size_t)(b * H_ + h) * 64 + d) * S_ + s0 + ss;
    *(uint4*)&dst[0] = *(uint4*)&o[0];
    *(uint4*)&dst[8] = *(uint4*)&o[8];
  }
}

// ---------------- flash attention: key-permuted QK^T, in-register P ---------
// Block = 8 waves x 16 q-rows = 128 q of one (b,h); paired q-tiles (15-bx, bx)
// -> uniform 36 KV-tiles/block, 256 blocks. K/V triple-buffered in LDS via
// global_load_lds, 2 tiles prefetch ahead, counted vmcnt. QK^T A-rows are
// PERMUTED so each lane's 16 scores are exactly its PV A-frag keys
// {g*8+0..7, 32+g*8+0..7}: softmax output packs straight into the PV MFMA
// operand with 8 cvt_pk — no LDS P round-trip.
__global__ __launch_bounds__(512) void attn_mfma(const u16* __restrict__ qkvb,
                                                 const u16* __restrict__ Vt,
                                                 u16* __restrict__ attb) {
  __shared__ u16 Ks[3][64 * 64];   // [key][dk], source-swizzled
  __shared__ u16 Vs[3][64 * 64];   // [dk][key], source-swizzled
  const int t = threadIdx.x;
  const int w = t >> 6, l = t & 63;
  const int g = l >> 4, ln = l & 15;
  const int h = blockIdx.y, b = blockIdx.z;
  const size_t bS = (size_t)b * S_;
  const u16* Kbase = qkvb + bS * NQKV + D_ + h * 64;          // row stride NQKV
  const u16* Vbase = Vt + (size_t)(b * H_ + h) * 64 * S_;     // row stride S_

  const int sr = t >> 3;                    // staged row 0..63
  const int ssx = (t & 7) ^ SWZ(sr);        // inverse-swizzled source slot
  auto stage = [&](int buf, int k0) {
    __builtin_amdgcn_global_load_lds(
        (gvptr)(Kbase + (size_t)(k0 + sr) * NQKV + ssx * 8),
        (lvptr)(&Ks[buf][w * 512]), 16, 0, 0);
    __builtin_amdgcn_global_load_lds(
        (gvptr)(Vbase + (size_t)sr * S_ + k0 + ssx * 8),
        (lvptr)(&Vs[buf][w * 512]), 16, 0, 0);
  };

  const f32x4 vzero = {0.f, 0.f, 0.f, 0.f};

#pragma unroll 1
  for (int half = 0; half < 2; ++half) {
    const int tq = (half == 0) ? (15 - blockIdx.x) : blockIdx.x;  // heavy first
    const int q0 = tq * 128;
    const int nt = 2 * tq + 2;
    const int qg = q0 + w * 16 + ln;
    const int wqmax = q0 + w * 16 + 15;

    short8 qf[2];
    {
      const u16* qrow = qkvb + (bS + q0 + w * 16 + ln) * NQKV + h * 64;
      qf[0] = *(const short8*)(qrow + g * 8);
      qf[1] = *(const short8*)(qrow + 32 + g * 8);
#pragma unroll
      for (int kx = 0; kx < 2; ++kx)
#pragma unroll
        for (int e = 0; e < 8; ++e)
          qf[kx][e] = (short)f2bf(bf2f((u16)qf[kx][e]) * QSCALE);
    }

    f32x4 o[4];
#pragma unroll
    for (int dt = 0; dt < 4; ++dt) o[dt] = vzero;
    float mrun = -INFINITY, lrun = 0.f;

    stage(0, 0);
    stage(1, 64);
    int cur = 0;

#pragma unroll 1
    for (int kt = 0; kt < nt; ++kt) {
      const int k0 = kt * 64;
      if (kt + 2 < nt) {
        int pre = cur + 2; if (pre >= 3) pre -= 3;
        stage(pre, k0 + 128);            // 2 loads issued; 2 tiles in flight
        asm volatile("s_waitcnt vmcnt(4)" ::: "memory");
      } else if (kt + 1 < nt) {
        asm volatile("s_waitcnt vmcnt(2)" ::: "memory");
      } else {
        asm volatile("s_waitcnt vmcnt(0)" ::: "memory");
      }
      RAW_BARRIER();                     // buf[cur] staged for all waves

      if (k0 <= wqmax) {                 // wave-uniform skip of irrelevant tiles
        // ---- QK^T with permuted A-rows ----
        f32x4 sacc[4];
#pragma unroll
        for (int st = 0; st < 4; ++st) sacc[st] = vzero;
        __builtin_amdgcn_s_setprio(1);
#pragma unroll
        for (int st = 0; st < 4; ++st) {
          const int pr = ((ln >> 2) << 3) + ((st & 1) << 2) + (ln & 3) + ((st >> 1) << 5);
#pragma unroll
          for (int ks = 0; ks < 2; ++ks) {
            short8 kf = *(const short8*)&Ks[cur][pr * 64 + (((ks * 4 + g) ^ SWZ(pr)) * 8)];
            sacc[st] = __builtin_amdgcn_mfma_f32_16x16x32_bf16(kf, qf[ks], sacc[st], 0, 0, 0);
          }
        }
        __builtin_amdgcn_s_setprio(0);

        // ---- online softmax; lane's key(st,r) = g*8+(st&1)*4+r+(st>>1)*32 ----
        float tmax = -INFINITY;
        if (k0 + 63 > q0 + w * 16) {     // tile may cross diagonal for this wave
#pragma unroll
          for (int st = 0; st < 4; ++st)
#pragma unroll
            for (int r = 0; r < 4; ++r) {
              int key = k0 + g * 8 + ((st & 1) << 2) + r + ((st >> 1) << 5);
              if (key > qg) sacc[st][r] = -INFINITY;
              tmax = fmaxf(tmax, sacc[st][r]);
            }
        } else {
#pragma unroll
          for (int st = 0; st < 4; ++st)
#pragma unroll
            for (int r = 0; r < 4; ++r) tmax = fmaxf(tmax, sacc[st][r]);
        }
        tmax = fmaxf(tmax, __shfl_xor(tmax, 16));
        tmax = fmaxf(tmax, __shfl_xor(tmax, 32));
        float al = 1.f, mnew = mrun;
        if (!__all(tmax <= mrun + 8.0f)) {   // defer-max (THR=8 in log2 units)
          mnew = fmaxf(mrun, tmax);
          al = EXP2F(mrun - mnew);
#pragma unroll
          for (int r = 0; r < 4; ++r) {
            float srs = __shfl(al, g * 4 + r);
#pragma unroll
            for (int dt = 0; dt < 4; ++dt) o[dt][r] *= srs;
          }
        }
        float lsum = 0.f;
#pragma unroll
        for (int st = 0; st < 4; ++st)
#pragma unroll
          for (int r = 0; r < 4; ++r) {
            float pe = EXP2F(sacc[st][r] - mnew);
            sacc[st][r] = pe;
            lsum += pe;
          }
        lsum += __shfl_xor(lsum, 16);
        lsum += __shfl_xor(lsum, 32);
        lrun = lrun * al + lsum;
        mrun = mnew;

        // ---- pack P into PV A-frags (in-lane, 8 cvt_pk) ----
        union { u32 u[4]; short8 v; } pa[2];
        pa[0].u[0] = cvtpk_bf16(sacc[0][0], sacc[0][1]);
        pa[0].u[1] = cvtpk_bf16(sacc[0][2], sacc[0][3]);
        pa[0].u[2] = cvtpk_bf16(sacc[1][0], sacc[1][1]);
        pa[0].u[3] = cvtpk_bf16(sacc[1][2], sacc[1][3]);
        pa[1].u[0] = cvtpk_bf16(sacc[2][0], sacc[2][1]);
        pa[1].u[1] = cvtpk_bf16(sacc[2][2], sacc[2][3]);
        pa[1].u[2] = cvtpk_bf16(sacc[3][0], sacc[3][1]);
        pa[1].u[3] = cvtpk_bf16(sacc[3][2], sacc[3][3]);

        // ---- PV: D[q][dk] ----
        __builtin_amdgcn_s_setprio(1);
#pragma unroll
        for (int ks = 0; ks < 2; ++ks)
#pragma unroll
          for (int dt = 0; dt < 4; ++dt) {
            const int dr = dt * 16 + ln;
            short8 vf = *(const short8*)&Vs[cur][dr * 64 + (((ks * 4 + g) ^ SWZ(dr)) * 8)];
            o[dt] = __builtin_amdgcn_mfma_f32_16x16x32_bf16(pa[ks].v, vf, o[dt], 0, 0, 0);
          }
        __builtin_amdgcn_s_setprio(0);
      }

      asm volatile("s_waitcnt lgkmcnt(0)" ::: "memory");
      RAW_BARRIER();                     // release buf[cur] for restaging
      cur = (cur == 2) ? 0 : cur + 1;
    }

    // ---- epilogue ----
    float linv = 1.f / lrun;
#pragma unroll
    for (int r = 0; r < 4; ++r) {
      float ir = __shfl(linv, g * 4 + r);
      size_t row = bS + q0 + w * 16 + g * 4 + r;
#pragma unroll
      for (int dt = 0; dt < 4; ++dt)
        attb[row * D_ + h * 64 + dt * 16 + ln] = f2bf(o[dt][r] * ir);
    }
    asm volatile("s_waitcnt vmcnt(0)" ::: "memory");  // clean count for next half
  }
}

// ---------------------------------------------------------------------------
extern "C" void kernel_launch(void* const* d_in, const int* in_sizes, int n_in,
                              void* d_out, int out_size, void* d_ws, size_t ws_size,
                              hipStream_t stream) {
  (void)in_sizes; (void)n_in; (void)out_size; (void)ws_size;
  const float* x   = (const float*)d_in[0];
  const int*   pos = (const int*)d_in[1];
  const float* w   = (const float*)d_in[2];   // (3,H,DK,D)
  const float* wo  = (const float*)d_in[3];   // (D, H*DK)
  float* out = (float*)d_out;

  u16* qkvb = (u16*)d_ws;                        // [4096][3072]
  u16* Vt   = qkvb + (size_t)M_ * NQKV;          // [2][16][64][2048]
  u16* attb = Vt + (size_t)B_ * H_ * 64 * S_;    // [4096][1024]
  u16* xb   = attb + (size_t)M_ * D_;            // [4096][1024]
  u16* wb   = xb + (size_t)M_ * D_;              // [3072][1024]  (contiguous after xb)
  u16* wob  = wb + (size_t)NQKV * D_;            // [1024][1024]  (contiguous after wb)
  float2* cstab = (float2*)(wob + (size_t)D_ * D_);  // [2048][32]

  rope_cs_kernel<<<(S_ * 32) / 256, 256, 0, stream>>>(pos, cstab);

  cvt_all_kernel<<<(N4X + N4W + N4WO) / 256, 256, 0, stream>>>(x, w, wo, xb);

  gemm_nt_mfma<true, true><<<dim3(NQKV / 128, M_ / 128), 256, 0, stream>>>(
      xb, wb, qkvb, cstab, NQKV, D_);

  v_transpose_kernel<<<dim3(S_ / 64, H_, B_), 256, 0, stream>>>(qkvb, Vt);

  attn_mfma<<<dim3(8, H_, B_), 512, 0, stream>>>(qkvb, Vt, attb);

  gemm_nt_mfma<false, false><<<dim3(D_ / 128, M_ / 128), 256, 0, stream>>>(
      attb, wob, out, nullptr, D_, D_);
}

// Round 7
// 203.238 us; speedup vs baseline: 7.9239x; 1.0241x over previous
//
#include <hip/hip_runtime.h>
#include <hip/hip_bf16.h>
#include <math.h>

#define B_   2
#define S_   2048
#define D_   1024
#define H_   16
#define DK_  64
#define NQKV 3072
#define M_   (B_ * S_)

typedef unsigned short u16;
typedef unsigned int   u32;
typedef __attribute__((ext_vector_type(8))) short short8;   // 8 bf16 (MFMA A/B frag)
typedef __attribute__((ext_vector_type(4))) float f32x4;    // MFMA C/D frag
typedef __attribute__((ext_vector_type(4))) u16   u16x4;

typedef const __attribute__((address_space(1))) void* gvptr;
typedef __attribute__((address_space(3))) void* lvptr;

// combined scale: 1/sqrt(64) * log2(e), so scores are in exp2 units directly
#define QSCALE 0.18033688011f

#if __has_builtin(__builtin_amdgcn_exp2f)
#define EXP2F(x) __builtin_amdgcn_exp2f(x)
#else
#define EXP2F(x) __expf(0.69314718056f * (x))
#endif

__device__ __forceinline__ u16 f2bf(float f) {
  union { float f; u32 u; } v; v.f = f;
  u32 r = v.u + 0x7FFF + ((v.u >> 16) & 1);   // RN-even
  return (u16)(r >> 16);
}
__device__ __forceinline__ float bf2f(u16 h) {
  union { u32 u; float f; } v; v.u = ((u32)h) << 16;
  return v.f;
}
__device__ __forceinline__ u32 cvtpk_bf16(float lo, float hi) {
  u32 r;
  asm("v_cvt_pk_bf16_f32 %0, %1, %2" : "=v"(r) : "v"(lo), "v"(hi));
  return r;
}

#define MEMFENCE() asm volatile("" ::: "memory")
#define RAW_BARRIER() do { MEMFENCE(); __builtin_amdgcn_s_barrier(); MEMFENCE(); } while (0)

// LDS row-swizzle for attn tiles
#define SWZ(r) ((((r) & 7) ^ ((((r) >> 3) & 1) << 2)))

// ---------------- RoPE cos/sin table (float2 per (s, pair)) -----------------
__global__ void rope_cs_kernel(const int* __restrict__ pos,
                               float2* __restrict__ cs) {
  int idx = blockIdx.x * 256 + threadIdx.x;   // S*32
  int i = idx & 31;
  int s = idx >> 5;
  double p = (double)pos[s];
  double t = p * pow(10000.0, -(double)i / 32.0);
  cs[idx] = make_float2((float)cos(t), (float)sin(t));
}

// ---------------- merged f32 -> bf16 convert for x, w, wo -------------------
#define N4X (M_ * D_ / 4)       // 1048576
#define N4W (NQKV * D_ / 4)     //  786432
#define N4WO (D_ * D_ / 4)      //  262144
__global__ void cvt_all_kernel(const float* __restrict__ x,
                               const float* __restrict__ w,
                               const float* __restrict__ wo,
                               u16* __restrict__ dst) {
  int i = blockIdx.x * 256 + threadIdx.x;
  float4 v;
  if (i < N4X)            v = ((const float4*)x)[i];
  else if (i < N4X + N4W) v = ((const float4*)w)[i - N4X];
  else                    v = ((const float4*)wo)[i - (N4X + N4W)];
  u16x4 o;
  o[0] = f2bf(v.x); o[1] = f2bf(v.y); o[2] = f2bf(v.z); o[3] = f2bf(v.w);
  ((u16x4*)dst)[i] = o;
}

// ---------------- bf16 MFMA GEMM, double-buffered counted-vmcnt pipeline ----
// C[M][N] = A[M][K] * Bm[N][K]^T. 128x128 tile, BK=64, 4 waves 2x2, 4x4 frags.
// Staging: global_load_lds 16B, linear LDS dest, inverse-swizzled SOURCE,
// XOR-swizzled ds_read (rule #21). Pipeline: stage tile t+1 while computing
// tile t; vmcnt(8) keeps next-tile loads in flight across the barrier
// (T3-minimum + T4); setprio(1) around MFMA cluster (T5).
template<bool OUT_BF16, bool ROPE>
__global__ __launch_bounds__(256) void gemm_nt_mfma(const u16* __restrict__ A,
                                                    const u16* __restrict__ Bm,
                                                    void* __restrict__ Cout,
                                                    const float2* __restrict__ cstab,
                                                    int Nd, int Kd) {
  __shared__ u16 As[2][128 * 64];
  __shared__ u16 Bs[2][128 * 64];
  const int t  = threadIdx.x;
  const int w  = t >> 6, l = t & 63;
  const int g  = l >> 4, ln = l & 15;
  const int wm = w >> 1, wn = w & 1;
  const int m0 = blockIdx.y * 128, n0 = blockIdx.x * 128;

  const int sr = t >> 3;                    // staged row (per 256-chunk)
  auto stage = [&](int buf, int k0) {
#pragma unroll
    for (int p = 0; p < 4; ++p) {
      int r = p * 32 + sr;
      int sx = (t & 7) ^ (r & 7);
      __builtin_amdgcn_global_load_lds(
          (gvptr)(A + (size_t)(m0 + r) * Kd + k0 + sx * 8),
          (lvptr)(&As[buf][(p * 256 + w * 64) * 8]), 16, 0, 0);
      __builtin_amdgcn_global_load_lds(
          (gvptr)(Bm + (size_t)(n0 + r) * Kd + k0 + sx * 8),
          (lvptr)(&Bs[buf][(p * 256 + w * 64) * 8]), 16, 0, 0);
    }
  };

  const f32x4 vzero = {0.f, 0.f, 0.f, 0.f};
  f32x4 acc[4][4];
#pragma unroll
  for (int i = 0; i < 4; ++i)
#pragma unroll
    for (int j = 0; j < 4; ++j) acc[i][j] = vzero;

  const int nkt = Kd >> 6;
  stage(0, 0);
  int cur = 0;
#pragma unroll 1
  for (int kt = 0; kt < nkt; ++kt) {
    if (kt + 1 < nkt) {
      stage(cur ^ 1, (kt + 1) * 64);       // 8 loads/thread stay in flight
      asm volatile("s_waitcnt vmcnt(8)" ::: "memory");
    } else {
      asm volatile("s_waitcnt vmcnt(0)" ::: "memory");
    }
    RAW_BARRIER();                         // buf[cur] fully staged

    __builtin_amdgcn_s_setprio(1);
#pragma unroll
    for (int ks = 0; ks < 2; ++ks) {
      short8 af[4], bf[4];
#pragma unroll
      for (int i = 0; i < 4; ++i) {
        int ra = wm * 64 + i * 16 + ln;
        af[i] = *(const short8*)&As[cur][ra * 64 + (((ks * 4 + g) ^ (ra & 7)) * 8)];
        int rb = wn * 64 + i * 16 + ln;
        bf[i] = *(const short8*)&Bs[cur][rb * 64 + (((ks * 4 + g) ^ (rb & 7)) * 8)];
      }
#pragma unroll
      for (int i = 0; i < 4; ++i)
#pragma unroll
        for (int j = 0; j < 4; ++j)
          acc[i][j] = __builtin_amdgcn_mfma_f32_16x16x32_bf16(af[i], bf[j], acc[i][j], 0, 0, 0);
    }
    __builtin_amdgcn_s_setprio(0);

    asm volatile("s_waitcnt lgkmcnt(0)" ::: "memory");
    RAW_BARRIER();                         // release buf[cur] for restaging
    cur ^= 1;
  }

  // epilogue: D row = wm*64+i*16+g*4+r, col = wn*64+j*16+ln
  if (ROPE && n0 < 2048) {   // q or k block: rotate pairs (even/odd cols)
#pragma unroll
    for (int i = 0; i < 4; ++i)
#pragma unroll
      for (int r = 0; r < 4; ++r) {
        int rowi = m0 + wm * 64 + i * 16 + g * 4 + r;
        int srow = rowi & (S_ - 1);
#pragma unroll
        for (int j = 0; j < 4; ++j) {
          int dk = j * 16 + ln;
          float2 cs = cstab[srow * 32 + (dk >> 1)];
          float v = acc[i][j][r];
          float p = __shfl_xor(v, 1);
          float sn = (ln & 1) ? cs.y : -cs.y;
          float rot = fmaf(p, sn, v * cs.x);
          ((u16*)Cout)[(size_t)rowi * Nd + n0 + wn * 64 + j * 16 + ln] = f2bf(rot);
        }
      }
  } else {
#pragma unroll
    for (int i = 0; i < 4; ++i)
#pragma unroll
      for (int j = 0; j < 4; ++j)
#pragma unroll
        for (int r = 0; r < 4; ++r) {
          size_t row = (size_t)(m0 + wm * 64 + i * 16 + g * 4 + r);
          size_t col = (size_t)(n0 + wn * 64 + j * 16 + ln);
          if (OUT_BF16) ((u16*)Cout)[row * Nd + col] = f2bf(acc[i][j][r]);
          else          ((float*)Cout)[row * Nd + col] = acc[i][j][r];
        }
  }
}

// ---------------- V transpose: qkv v-part -> Vt[b][h][dk][s] ----------------
__global__ __launch_bounds__(256) void v_transpose_kernel(const u16* __restrict__ qkvb,
                                                          u16* __restrict__ Vt) {
  __shared__ u16 tile[64][72];
  const int t = threadIdx.x;
  const int s0 = blockIdx.x * 64, h = blockIdx.y, b = blockIdx.z;
  {
    int r = t >> 2, cs = (t & 3) * 16;
    const u16* src = qkvb + (size_t)(b * S_ + s0 + r) * NQKV + 2048 + h * 64 + cs;
    u16 v[16];
    *(uint4*)&v[0] = *(const uint4*)src;
    *(uint4*)&v[8] = *(const uint4*)(src + 8);
#pragma unroll
    for (int j = 0; j < 16; ++j) tile[cs + j][r] = v[j];
  }
  __syncthreads();
  {
    int d = t >> 2, ss = (t & 3) * 16;
    u16 o[16];
#pragma unroll
    for (int j = 0; j < 16; ++j) o[j] = tile[d][ss + j];
    u16* dst = Vt + ((size_t)(b * H_ + h) * 64 + d) * S_ + s0 + ss;
    *(uint4*)&dst[0] = *(uint4*)&o[0];
    *(uint4*)&dst[8] = *(uint4*)&o[8];
  }
}

// ---------------- flash attention: key-permuted QK^T, in-register P ---------
// Block = 8 waves x 16 q-rows = 128 q of one (b,h); paired q-tiles (15-bx, bx)
// -> uniform 36 KV-tiles/block, 256 blocks. K/V triple-buffered in LDS via
// global_load_lds, 2 tiles prefetch ahead, counted vmcnt. QK^T A-rows are
// PERMUTED so each lane's 16 scores are exactly its PV A-frag keys
// {g*8+0..7, 32+g*8+0..7}: softmax output packs straight into the PV MFMA
// operand with 8 cvt_pk — no LDS P round-trip.
__global__ __launch_bounds__(512) void attn_mfma(const u16* __restrict__ qkvb,
                                                 const u16* __restrict__ Vt,
                                                 u16* __restrict__ attb) {
  __shared__ u16 Ks[3][64 * 64];   // [key][dk], source-swizzled
  __shared__ u16 Vs[3][64 * 64];   // [dk][key], source-swizzled
  const int t = threadIdx.x;
  const int w = t >> 6, l = t & 63;
  const int g = l >> 4, ln = l & 15;
  const int h = blockIdx.y, b = blockIdx.z;
  const size_t bS = (size_t)b * S_;
  const u16* Kbase = qkvb + bS * NQKV + D_ + h * 64;          // row stride NQKV
  const u16* Vbase = Vt + (size_t)(b * H_ + h) * 64 * S_;     // row stride S_

  const int sr = t >> 3;                    // staged row 0..63
  const int ssx = (t & 7) ^ SWZ(sr);        // inverse-swizzled source slot
  auto stage = [&](int buf, int k0) {
    __builtin_amdgcn_global_load_lds(
        (gvptr)(Kbase + (size_t)(k0 + sr) * NQKV + ssx * 8),
        (lvptr)(&Ks[buf][w * 512]), 16, 0, 0);
    __builtin_amdgcn_global_load_lds(
        (gvptr)(Vbase + (size_t)sr * S_ + k0 + ssx * 8),
        (lvptr)(&Vs[buf][w * 512]), 16, 0, 0);
  };

  const f32x4 vzero = {0.f, 0.f, 0.f, 0.f};

#pragma unroll 1
  for (int half = 0; half < 2; ++half) {
    const int tq = (half == 0) ? (15 - blockIdx.x) : blockIdx.x;  // heavy first
    const int q0 = tq * 128;
    const int nt = 2 * tq + 2;
    const int qg = q0 + w * 16 + ln;
    const int wqmax = q0 + w * 16 + 15;

    short8 qf[2];
    {
      const u16* qrow = qkvb + (bS + q0 + w * 16 + ln) * NQKV + h * 64;
      qf[0] = *(const short8*)(qrow + g * 8);
      qf[1] = *(const short8*)(qrow + 32 + g * 8);
#pragma unroll
      for (int kx = 0; kx < 2; ++kx)
#pragma unroll
        for (int e = 0; e < 8; ++e)
          qf[kx][e] = (short)f2bf(bf2f((u16)qf[kx][e]) * QSCALE);
    }

    f32x4 o[4];
#pragma unroll
    for (int dt = 0; dt < 4; ++dt) o[dt] = vzero;
    float mrun = -INFINITY, lrun = 0.f;

    stage(0, 0);
    stage(1, 64);
    int cur = 0;

#pragma unroll 1
    for (int kt = 0; kt < nt; ++kt) {
      const int k0 = kt * 64;
      if (kt + 2 < nt) {
        int pre = cur + 2; if (pre >= 3) pre -= 3;
        stage(pre, k0 + 128);            // 2 loads issued; 2 tiles in flight
        asm volatile("s_waitcnt vmcnt(4)" ::: "memory");
      } else if (kt + 1 < nt) {
        asm volatile("s_waitcnt vmcnt(2)" ::: "memory");
      } else {
        asm volatile("s_waitcnt vmcnt(0)" ::: "memory");
      }
      RAW_BARRIER();                     // buf[cur] staged for all waves

      if (k0 <= wqmax) {                 // wave-uniform skip of irrelevant tiles
        // ---- QK^T with permuted A-rows ----
        f32x4 sacc[4];
#pragma unroll
        for (int st = 0; st < 4; ++st) sacc[st] = vzero;
        __builtin_amdgcn_s_setprio(1);
#pragma unroll
        for (int st = 0; st < 4; ++st) {
          const int pr = ((ln >> 2) << 3) + ((st & 1) << 2) + (ln & 3) + ((st >> 1) << 5);
#pragma unroll
          for (int ks = 0; ks < 2; ++ks) {
            short8 kf = *(const short8*)&Ks[cur][pr * 64 + (((ks * 4 + g) ^ SWZ(pr)) * 8)];
            sacc[st] = __builtin_amdgcn_mfma_f32_16x16x32_bf16(kf, qf[ks], sacc[st], 0, 0, 0);
          }
        }
        __builtin_amdgcn_s_setprio(0);

        // ---- online softmax; lane's key(st,r) = g*8+(st&1)*4+r+(st>>1)*32 ----
        float tmax = -INFINITY;
        if (k0 + 63 > q0 + w * 16) {     // tile may cross diagonal for this wave
#pragma unroll
          for (int st = 0; st < 4; ++st)
#pragma unroll
            for (int r = 0; r < 4; ++r) {
              int key = k0 + g * 8 + ((st & 1) << 2) + r + ((st >> 1) << 5);
              if (key > qg) sacc[st][r] = -INFINITY;
              tmax = fmaxf(tmax, sacc[st][r]);
            }
        } else {
#pragma unroll
          for (int st = 0; st < 4; ++st)
#pragma unroll
            for (int r = 0; r < 4; ++r) tmax = fmaxf(tmax, sacc[st][r]);
        }
        tmax = fmaxf(tmax, __shfl_xor(tmax, 16));
        tmax = fmaxf(tmax, __shfl_xor(tmax, 32));
        float al = 1.f, mnew = mrun;
        if (!__all(tmax <= mrun + 8.0f)) {   // defer-max (THR=8 in log2 units)
          mnew = fmaxf(mrun, tmax);
          al = EXP2F(mrun - mnew);
#pragma unroll
          for (int r = 0; r < 4; ++r) {
            float srs = __shfl(al, g * 4 + r);
#pragma unroll
            for (int dt = 0; dt < 4; ++dt) o[dt][r] *= srs;
          }
        }
        float lsum = 0.f;
#pragma unroll
        for (int st = 0; st < 4; ++st)
#pragma unroll
          for (int r = 0; r < 4; ++r) {
            float pe = EXP2F(sacc[st][r] - mnew);
            sacc[st][r] = pe;
            lsum += pe;
          }
        lsum += __shfl_xor(lsum, 16);
        lsum += __shfl_xor(lsum, 32);
        lrun = lrun * al + lsum;
        mrun = mnew;

        // ---- pack P into PV A-frags (in-lane, 8 cvt_pk) ----
        union { u32 u[4]; short8 v; } pa[2];
        pa[0].u[0] = cvtpk_bf16(sacc[0][0], sacc[0][1]);
        pa[0].u[1] = cvtpk_bf16(sacc[0][2], sacc[0][3]);
        pa[0].u[2] = cvtpk_bf16(sacc[1][0], sacc[1][1]);
        pa[0].u[3] = cvtpk_bf16(sacc[1][2], sacc[1][3]);
        pa[1].u[0] = cvtpk_bf16(sacc[2][0], sacc[2][1]);
        pa[1].u[1] = cvtpk_bf16(sacc[2][2], sacc[2][3]);
        pa[1].u[2] = cvtpk_bf16(sacc[3][0], sacc[3][1]);
        pa[1].u[3] = cvtpk_bf16(sacc[3][2], sacc[3][3]);

        // ---- PV: D[q][dk] ----
        __builtin_amdgcn_s_setprio(1);
#pragma unroll
        for (int ks = 0; ks < 2; ++ks)
#pragma unroll
          for (int dt = 0; dt < 4; ++dt) {
            const int dr = dt * 16 + ln;
            short8 vf = *(const short8*)&Vs[cur][dr * 64 + (((ks * 4 + g) ^ SWZ(dr)) * 8)];
            o[dt] = __builtin_amdgcn_mfma_f32_16x16x32_bf16(pa[ks].v, vf, o[dt], 0, 0, 0);
          }
        __builtin_amdgcn_s_setprio(0);
      }

      asm volatile("s_waitcnt lgkmcnt(0)" ::: "memory");
      RAW_BARRIER();                     // release buf[cur] for restaging
      cur = (cur == 2) ? 0 : cur + 1;
    }

    // ---- epilogue ----
    float linv = 1.f / lrun;
#pragma unroll
    for (int r = 0; r < 4; ++r) {
      float ir = __shfl(linv, g * 4 + r);
      size_t row = bS + q0 + w * 16 + g * 4 + r;
#pragma unroll
      for (int dt = 0; dt < 4; ++dt)
        attb[row * D_ + h * 64 + dt * 16 + ln] = f2bf(o[dt][r] * ir);
    }
    asm volatile("s_waitcnt vmcnt(0)" ::: "memory");  // clean count for next half
  }
}

// ---------------------------------------------------------------------------
extern "C" void kernel_launch(void* const* d_in, const int* in_sizes, int n_in,
                              void* d_out, int out_size, void* d_ws, size_t ws_size,
                              hipStream_t stream) {
  (void)in_sizes; (void)n_in; (void)out_size; (void)ws_size;
  const float* x   = (const float*)d_in[0];
  const int*   pos = (const int*)d_in[1];
  const float* w   = (const float*)d_in[2];   // (3,H,DK,D)
  const float* wo  = (const float*)d_in[3];   // (D, H*DK)
  float* out = (float*)d_out;

  u16* qkvb = (u16*)d_ws;                        // [4096][3072]
  u16* Vt   = qkvb + (size_t)M_ * NQKV;          // [2][16][64][2048]
  u16* attb = Vt + (size_t)B_ * H_ * 64 * S_;    // [4096][1024]
  u16* xb   = attb + (size_t)M_ * D_;            // [4096][1024]
  u16* wb   = xb + (size_t)M_ * D_;              // [3072][1024]  (contiguous after xb)
  u16* wob  = wb + (size_t)NQKV * D_;            // [1024][1024]  (contiguous after wb)
  float2* cstab = (float2*)(wob + (size_t)D_ * D_);  // [2048][32]

  rope_cs_kernel<<<(S_ * 32) / 256, 256, 0, stream>>>(pos, cstab);

  cvt_all_kernel<<<(N4X + N4W + N4WO) / 256, 256, 0, stream>>>(x, w, wo, xb);

  gemm_nt_mfma<true, true><<<dim3(NQKV / 128, M_ / 128), 256, 0, stream>>>(
      xb, wb, qkvb, cstab, NQKV, D_);

  v_transpose_kernel<<<dim3(S_ / 64, H_, B_), 256, 0, stream>>>(qkvb, Vt);

  attn_mfma<<<dim3(8, H_, B_), 512, 0, stream>>>(qkvb, Vt, attb);

  gemm_nt_mfma<false, false><<<dim3(D_ / 128, M_ / 128), 256, 0, stream>>>(
      attb, wob, out, nullptr, D_, D_);
}

// Round 8
// 189.318 us; speedup vs baseline: 8.5065x; 1.0735x over previous
//
#include <hip/hip_runtime.h>
#include <hip/hip_bf16.h>
#include <math.h>

#define B_   2
#define S_   2048
#define D_   1024
#define H_   16
#define DK_  64
#define NQKV 3072
#define M_   (B_ * S_)

typedef unsigned short u16;
typedef unsigned int   u32;
typedef __attribute__((ext_vector_type(8))) short short8;   // 8 bf16 (MFMA A/B frag)
typedef __attribute__((ext_vector_type(4))) float f32x4;    // MFMA C/D frag
typedef __attribute__((ext_vector_type(4))) u16   u16x4;

typedef const __attribute__((address_space(1))) void* gvptr;
typedef __attribute__((address_space(3))) void* lvptr;

// combined scale: 1/sqrt(64) * log2(e), so scores are in exp2 units directly
#define QSCALE 0.18033688011f

#if __has_builtin(__builtin_amdgcn_exp2f)
#define EXP2F(x) __builtin_amdgcn_exp2f(x)
#else
#define EXP2F(x) __expf(0.69314718056f * (x))
#endif

__device__ __forceinline__ u16 f2bf(float f) {
  union { float f; u32 u; } v; v.f = f;
  u32 r = v.u + 0x7FFF + ((v.u >> 16) & 1);   // RN-even
  return (u16)(r >> 16);
}
__device__ __forceinline__ float bf2f(u16 h) {
  union { u32 u; float f; } v; v.u = ((u32)h) << 16;
  return v.f;
}
__device__ __forceinline__ u32 cvtpk_bf16(float lo, float hi) {
  u32 r;
  asm("v_cvt_pk_bf16_f32 %0, %1, %2" : "=v"(r) : "v"(lo), "v"(hi));
  return r;
}

#define MEMFENCE() asm volatile("" ::: "memory")
#define RAW_BARRIER() do { MEMFENCE(); __builtin_amdgcn_s_barrier(); MEMFENCE(); } while (0)

// 8-slot row swizzle (128B rows: K tiles, GEMM tiles)
#define SWZ(r) ((((r) & 7) ^ ((((r) >> 3) & 1) << 2)))

// ---------------- RoPE cos/sin table (float2 per (s, pair)) -----------------
__global__ void rope_cs_kernel(const int* __restrict__ pos,
                               float2* __restrict__ cs) {
  int idx = blockIdx.x * 256 + threadIdx.x;   // S*32
  int i = idx & 31;
  int s = idx >> 5;
  double p = (double)pos[s];
  double t = p * pow(10000.0, -(double)i / 32.0);
  cs[idx] = make_float2((float)cos(t), (float)sin(t));
}

// ---------------- merged f32 -> bf16 convert for x, w, wo -------------------
#define N4X (M_ * D_ / 4)       // 1048576
#define N4W (NQKV * D_ / 4)     //  786432
#define N4WO (D_ * D_ / 4)      //  262144
__global__ void cvt_all_kernel(const float* __restrict__ x,
                               const float* __restrict__ w,
                               const float* __restrict__ wo,
                               u16* __restrict__ dst) {
  int i = blockIdx.x * 256 + threadIdx.x;
  float4 v;
  if (i < N4X)            v = ((const float4*)x)[i];
  else if (i < N4X + N4W) v = ((const float4*)w)[i - N4X];
  else                    v = ((const float4*)wo)[i - (N4X + N4W)];
  u16x4 o;
  o[0] = f2bf(v.x); o[1] = f2bf(v.y); o[2] = f2bf(v.z); o[3] = f2bf(v.w);
  ((u16x4*)dst)[i] = o;
}

// ---------------- bf16 MFMA GEMM 128x128 (GEMM1), dbuf counted-vmcnt --------
template<bool OUT_BF16, bool ROPE>
__global__ __launch_bounds__(256) void gemm_nt_mfma(const u16* __restrict__ A,
                                                    const u16* __restrict__ Bm,
                                                    void* __restrict__ Cout,
                                                    const float2* __restrict__ cstab,
                                                    int Nd, int Kd) {
  __shared__ u16 As[2][128 * 64];
  __shared__ u16 Bs[2][128 * 64];
  const int t  = threadIdx.x;
  const int w  = t >> 6, l = t & 63;
  const int g  = l >> 4, ln = l & 15;
  const int wm = w >> 1, wn = w & 1;
  const int m0 = blockIdx.y * 128, n0 = blockIdx.x * 128;

  const int sr = t >> 3;
  auto stage = [&](int buf, int k0) {
#pragma unroll
    for (int p = 0; p < 4; ++p) {
      int r = p * 32 + sr;
      int sx = (t & 7) ^ (r & 7);
      __builtin_amdgcn_global_load_lds(
          (gvptr)(A + (size_t)(m0 + r) * Kd + k0 + sx * 8),
          (lvptr)(&As[buf][(p * 256 + w * 64) * 8]), 16, 0, 0);
      __builtin_amdgcn_global_load_lds(
          (gvptr)(Bm + (size_t)(n0 + r) * Kd + k0 + sx * 8),
          (lvptr)(&Bs[buf][(p * 256 + w * 64) * 8]), 16, 0, 0);
    }
  };

  const f32x4 vzero = {0.f, 0.f, 0.f, 0.f};
  f32x4 acc[4][4];
#pragma unroll
  for (int i = 0; i < 4; ++i)
#pragma unroll
    for (int j = 0; j < 4; ++j) acc[i][j] = vzero;

  const int nkt = Kd >> 6;
  stage(0, 0);
  int cur = 0;
#pragma unroll 1
  for (int kt = 0; kt < nkt; ++kt) {
    if (kt + 1 < nkt) {
      stage(cur ^ 1, (kt + 1) * 64);
      asm volatile("s_waitcnt vmcnt(8)" ::: "memory");
    } else {
      asm volatile("s_waitcnt vmcnt(0)" ::: "memory");
    }
    RAW_BARRIER();

    __builtin_amdgcn_s_setprio(1);
#pragma unroll
    for (int ks = 0; ks < 2; ++ks) {
      short8 af[4], bf[4];
#pragma unroll
      for (int i = 0; i < 4; ++i) {
        int ra = wm * 64 + i * 16 + ln;
        af[i] = *(const short8*)&As[cur][ra * 64 + (((ks * 4 + g) ^ (ra & 7)) * 8)];
        int rb = wn * 64 + i * 16 + ln;
        bf[i] = *(const short8*)&Bs[cur][rb * 64 + (((ks * 4 + g) ^ (rb & 7)) * 8)];
      }
#pragma unroll
      for (int i = 0; i < 4; ++i)
#pragma unroll
        for (int j = 0; j < 4; ++j)
          acc[i][j] = __builtin_amdgcn_mfma_f32_16x16x32_bf16(af[i], bf[j], acc[i][j], 0, 0, 0);
    }
    __builtin_amdgcn_s_setprio(0);

    asm volatile("s_waitcnt lgkmcnt(0)" ::: "memory");
    RAW_BARRIER();
    cur ^= 1;
  }

  if (ROPE && n0 < 2048) {   // q or k block: rotate pairs (even/odd cols)
#pragma unroll
    for (int i = 0; i < 4; ++i)
#pragma unroll
      for (int r = 0; r < 4; ++r) {
        int rowi = m0 + wm * 64 + i * 16 + g * 4 + r;
        int srow = rowi & (S_ - 1);
#pragma unroll
        for (int j = 0; j < 4; ++j) {
          int dk = j * 16 + ln;
          float2 cs = cstab[srow * 32 + (dk >> 1)];
          float v = acc[i][j][r];
          float p = __shfl_xor(v, 1);
          float sn = (ln & 1) ? cs.y : -cs.y;
          float rot = fmaf(p, sn, v * cs.x);
          ((u16*)Cout)[(size_t)rowi * Nd + n0 + wn * 64 + j * 16 + ln] = f2bf(rot);
        }
      }
  } else {
#pragma unroll
    for (int i = 0; i < 4; ++i)
#pragma unroll
      for (int j = 0; j < 4; ++j)
#pragma unroll
        for (int r = 0; r < 4; ++r) {
          size_t row = (size_t)(m0 + wm * 64 + i * 16 + g * 4 + r);
          size_t col = (size_t)(n0 + wn * 64 + j * 16 + ln);
          if (OUT_BF16) ((u16*)Cout)[row * Nd + col] = f2bf(acc[i][j][r]);
          else          ((float*)Cout)[row * Nd + col] = acc[i][j][r];
        }
  }
}

// ---------------- bf16 MFMA GEMM 64x64 (GEMM2): 1024 blocks = 4/CU ----------
// GEMM2 was 1 block/CU latency-bound. 64x64 tile, 4 waves of 32x32 (2x2 frags),
// dbuf + counted vmcnt. f32 output.
__global__ __launch_bounds__(256) void gemm_small_mfma(const u16* __restrict__ A,
                                                       const u16* __restrict__ Bm,
                                                       float* __restrict__ C,
                                                       int Nd, int Kd) {
  __shared__ u16 As[2][64 * 64];
  __shared__ u16 Bs[2][64 * 64];
  const int t  = threadIdx.x;
  const int w  = t >> 6, l = t & 63;
  const int g  = l >> 4, ln = l & 15;
  const int wm = w >> 1, wn = w & 1;
  const int m0 = blockIdx.y * 64, n0 = blockIdx.x * 64;

  auto stage = [&](int buf, int k0) {
#pragma unroll
    for (int p = 0; p < 2; ++p) {
      int c = p * 256 + t;
      int r = c >> 3;
      int sx = (c & 7) ^ (r & 7);
      __builtin_amdgcn_global_load_lds(
          (gvptr)(A + (size_t)(m0 + r) * Kd + k0 + sx * 8),
          (lvptr)(&As[buf][(p * 256 + w * 64) * 8]), 16, 0, 0);
      __builtin_amdgcn_global_load_lds(
          (gvptr)(Bm + (size_t)(n0 + r) * Kd + k0 + sx * 8),
          (lvptr)(&Bs[buf][(p * 256 + w * 64) * 8]), 16, 0, 0);
    }
  };

  const f32x4 vzero = {0.f, 0.f, 0.f, 0.f};
  f32x4 acc[2][2];
#pragma unroll
  for (int i = 0; i < 2; ++i)
#pragma unroll
    for (int j = 0; j < 2; ++j) acc[i][j] = vzero;

  const int nkt = Kd >> 6;
  stage(0, 0);
  int cur = 0;
#pragma unroll 1
  for (int kt = 0; kt < nkt; ++kt) {
    if (kt + 1 < nkt) {
      stage(cur ^ 1, (kt + 1) * 64);       // 4 loads/thread in flight
      asm volatile("s_waitcnt vmcnt(4)" ::: "memory");
    } else {
      asm volatile("s_waitcnt vmcnt(0)" ::: "memory");
    }
    RAW_BARRIER();

    __builtin_amdgcn_s_setprio(1);
#pragma unroll
    for (int ks = 0; ks < 2; ++ks) {
      short8 af[2], bf[2];
#pragma unroll
      for (int i = 0; i < 2; ++i) {
        int ra = wm * 32 + i * 16 + ln;
        af[i] = *(const short8*)&As[cur][ra * 64 + (((ks * 4 + g) ^ (ra & 7)) * 8)];
        int rb = wn * 32 + i * 16 + ln;
        bf[i] = *(const short8*)&Bs[cur][rb * 64 + (((ks * 4 + g) ^ (rb & 7)) * 8)];
      }
#pragma unroll
      for (int i = 0; i < 2; ++i)
#pragma unroll
        for (int j = 0; j < 2; ++j)
          acc[i][j] = __builtin_amdgcn_mfma_f32_16x16x32_bf16(af[i], bf[j], acc[i][j], 0, 0, 0);
    }
    __builtin_amdgcn_s_setprio(0);

    asm volatile("s_waitcnt lgkmcnt(0)" ::: "memory");
    RAW_BARRIER();
    cur ^= 1;
  }

#pragma unroll
  for (int i = 0; i < 2; ++i)
#pragma unroll
    for (int j = 0; j < 2; ++j)
#pragma unroll
      for (int r = 0; r < 4; ++r)
        C[(size_t)(m0 + wm * 32 + i * 16 + g * 4 + r) * Nd + n0 + wn * 32 + j * 16 + ln]
            = acc[i][j][r];
}

// ---------------- V transpose: qkv v-part -> Vt[b][h][dk][s] ----------------
__global__ __launch_bounds__(256) void v_transpose_kernel(const u16* __restrict__ qkvb,
                                                          u16* __restrict__ Vt) {
  __shared__ u16 tile[64][72];
  const int t = threadIdx.x;
  const int s0 = blockIdx.x * 64, h = blockIdx.y, b = blockIdx.z;
  {
    int r = t >> 2, cs = (t & 3) * 16;
    const u16* src = qkvb + (size_t)(b * S_ + s0 + r) * NQKV + 2048 + h * 64 + cs;
    u16 v[16];
    *(uint4*)&v[0] = *(const uint4*)src;
    *(uint4*)&v[8] = *(const uint4*)(src + 8);
#pragma unroll
    for (int j = 0; j < 16; ++j) tile[cs + j][r] = v[j];
  }
  __syncthreads();
  {
    int d = t >> 2, ss = (t & 3) * 16;
    u16 o[16];
#pragma unroll
    for (int j = 0; j < 16; ++j) o[j] = tile[d][ss + j];
    u16* dst = Vt + ((size_t)(b * H_ + h) * 64 + d) * S_ + s0 + ss;
    *(uint4*)&dst[0] = *(uint4*)&o[0];
    *(uint4*)&dst[8] = *(uint4*)&o[8];
  }
}

// ---------------- flash attention: merged-pair single KV pass, KVBLK=128 ----
// Block = q-tiles {15-bx (heavy), bx (light)} of one (b,h); ONE pass over the
// heavy tile's KV range; each staged 128-key tile feeds BOTH chains (light
// skips tiles beyond its diagonal). Two independent QK->SM->PV streams per
// wave give cross-chain MFMA/VALU ILP; 128-key tiles halve barrier density
// (34 -> 16-bx barrier-tiles per block). K rows 128B use 8-slot XOR swizzle;
// V rows 256B use 16-slot XOR swizzle (rv&15) -> PV reads conflict-free.
__global__ __launch_bounds__(512) void attn_mfma(const u16* __restrict__ qkvb,
                                                 const u16* __restrict__ Vt,
                                                 u16* __restrict__ attb) {
  __shared__ u16 Ks[2][128 * 64];   // [key][dk]
  __shared__ u16 Vs[2][64 * 128];   // [dk][key]
  const int t = threadIdx.x;
  const int w = t >> 6, l = t & 63;
  const int g = l >> 4, ln = l & 15;
  const int bx = blockIdx.x, h = blockIdx.y, b = blockIdx.z;
  const size_t bS = (size_t)b * S_;
  const u16* Kbase = qkvb + bS * NQKV + D_ + h * 64;          // row stride NQKV
  const u16* Vbase = Vt + (size_t)(b * H_ + h) * 64 * S_;     // row stride S_

  // staging: per thread 2 K-chunks + 2 V-chunks (16B each)
  auto stage = [&](int buf, int k0) {
#pragma unroll
    for (int p = 0; p < 2; ++p) {
      int ck = p * 512 + t;                 // K chunk 0..1023
      int rk = ck >> 3, sk = (ck & 7) ^ SWZ(rk);
      __builtin_amdgcn_global_load_lds(
          (gvptr)(Kbase + (size_t)(k0 + rk) * NQKV + sk * 8),
          (lvptr)(&Ks[buf][(p * 512 + w * 64) * 8]), 16, 0, 0);
      int cv = p * 512 + t;                 // V chunk 0..1023
      int rv = cv >> 4, sv = (cv & 15) ^ (rv & 15);
      __builtin_amdgcn_global_load_lds(
          (gvptr)(Vbase + (size_t)rv * S_ + k0 + sv * 8),
          (lvptr)(&Vs[buf][(p * 512 + w * 64) * 8]), 16, 0, 0);
    }
  };

  const f32x4 vzero = {0.f, 0.f, 0.f, 0.f};

  const int tqH = 15 - bx, tqL = bx;
  const int q0H = tqH * 128, q0L = tqL * 128;
  const int nt = 16 - bx;                   // heavy pass length (128-key tiles)
  const int ntL = bx + 1;                   // light active tiles
  const int qgH = q0H + w * 16 + ln;
  const int qgL = q0L + w * 16 + ln;

  short8 qfH[2], qfL[2];
  {
    const u16* qr = qkvb + (bS + q0H + w * 16 + ln) * NQKV + h * 64;
    qfH[0] = *(const short8*)(qr + g * 8);
    qfH[1] = *(const short8*)(qr + 32 + g * 8);
    qr = qkvb + (bS + q0L + w * 16 + ln) * NQKV + h * 64;
    qfL[0] = *(const short8*)(qr + g * 8);
    qfL[1] = *(const short8*)(qr + 32 + g * 8);
#pragma unroll
    for (int kx = 0; kx < 2; ++kx)
#pragma unroll
      for (int e = 0; e < 8; ++e) {
        qfH[kx][e] = (short)f2bf(bf2f((u16)qfH[kx][e]) * QSCALE);
        qfL[kx][e] = (short)f2bf(bf2f((u16)qfL[kx][e]) * QSCALE);
      }
  }

  f32x4 oH[4], oL[4];
#pragma unroll
  for (int dt = 0; dt < 4; ++dt) { oH[dt] = vzero; oL[dt] = vzero; }
  float mH = -INFINITY, lH = 0.f, mL = -INFINITY, lL = 0.f;

  // one chain step: QK(16 MFMA) -> online SM -> pack -> PV(16 MFMA)
  auto chain = [&](const short8* qf, f32x4* o, float& mrun, float& lrun,
                   int qg, bool maskTile, int k0, int cur) {
    f32x4 sacc[8];
#pragma unroll
    for (int st = 0; st < 8; ++st) sacc[st] = vzero;
    __builtin_amdgcn_s_setprio(1);
#pragma unroll
    for (int st = 0; st < 8; ++st) {
      const int pr = ((ln >> 2) << 3) + ((st & 1) << 2) + (ln & 3) + ((st >> 1) << 5);
#pragma unroll
      for (int ks = 0; ks < 2; ++ks) {
        short8 kf = *(const short8*)&Ks[cur][pr * 64 + (((ks * 4 + g) ^ SWZ(pr)) * 8)];
        sacc[st] = __builtin_amdgcn_mfma_f32_16x16x32_bf16(kf, qf[ks], sacc[st], 0, 0, 0);
      }
    }
    __builtin_amdgcn_s_setprio(0);

    float tmax = -INFINITY;
    if (maskTile) {
#pragma unroll
      for (int st = 0; st < 8; ++st)
#pragma unroll
        for (int r = 0; r < 4; ++r) {
          int key = k0 + g * 8 + ((st & 1) << 2) + r + ((st >> 1) << 5);
          if (key > qg) sacc[st][r] = -INFINITY;
          tmax = fmaxf(tmax, sacc[st][r]);
        }
    } else {
#pragma unroll
      for (int st = 0; st < 8; ++st)
#pragma unroll
        for (int r = 0; r < 4; ++r) tmax = fmaxf(tmax, sacc[st][r]);
    }
    tmax = fmaxf(tmax, __shfl_xor(tmax, 16));
    tmax = fmaxf(tmax, __shfl_xor(tmax, 32));
    float al = 1.f, mnew = mrun;
    if (!__all(tmax <= mrun + 8.0f)) {       // defer-max (THR=8 in log2 units)
      mnew = fmaxf(mrun, tmax);
      al = EXP2F(mrun - mnew);
#pragma unroll
      for (int r = 0; r < 4; ++r) {
        float srs = __shfl(al, g * 4 + r);
#pragma unroll
        for (int dt = 0; dt < 4; ++dt) o[dt][r] *= srs;
      }
    }
    float lsum = 0.f;
#pragma unroll
    for (int st = 0; st < 8; ++st)
#pragma unroll
      for (int r = 0; r < 4; ++r) {
        float pe = EXP2F(sacc[st][r] - mnew);
        sacc[st][r] = pe;
        lsum += pe;
      }
    lsum += __shfl_xor(lsum, 16);
    lsum += __shfl_xor(lsum, 32);
    lrun = lrun * al + lsum;
    mrun = mnew;

    union { u32 u[4]; short8 v; } pa[4];
#pragma unroll
    for (int ks = 0; ks < 4; ++ks) {
      pa[ks].u[0] = cvtpk_bf16(sacc[2 * ks][0], sacc[2 * ks][1]);
      pa[ks].u[1] = cvtpk_bf16(sacc[2 * ks][2], sacc[2 * ks][3]);
      pa[ks].u[2] = cvtpk_bf16(sacc[2 * ks + 1][0], sacc[2 * ks + 1][1]);
      pa[ks].u[3] = cvtpk_bf16(sacc[2 * ks + 1][2], sacc[2 * ks + 1][3]);
    }

    __builtin_amdgcn_s_setprio(1);
#pragma unroll
    for (int ks = 0; ks < 4; ++ks)
#pragma unroll
      for (int dt = 0; dt < 4; ++dt) {
        const int dr = dt * 16 + ln;
        short8 vf = *(const short8*)&Vs[cur][dr * 128 + (((ks * 4 + g) ^ (dr & 15)) * 8)];
        o[dt] = __builtin_amdgcn_mfma_f32_16x16x32_bf16(pa[ks].v, vf, o[dt], 0, 0, 0);
      }
    __builtin_amdgcn_s_setprio(0);
  };

  stage(0, 0);
  int cur = 0;
#pragma unroll 1
  for (int kt = 0; kt < nt; ++kt) {
    const int k0 = kt * 128;
    if (kt + 1 < nt) {
      stage(cur ^ 1, k0 + 128);            // 4 loads/thread in flight
      asm volatile("s_waitcnt vmcnt(4)" ::: "memory");
    } else {
      asm volatile("s_waitcnt vmcnt(0)" ::: "memory");
    }
    RAW_BARRIER();                         // buf[cur] staged

    chain(qfH, oH, mH, lH, qgH, kt == nt - 1, k0, cur);
    if (kt < ntL)
      chain(qfL, oL, mL, lL, qgL, kt == tqL, k0, cur);

    asm volatile("s_waitcnt lgkmcnt(0)" ::: "memory");
    RAW_BARRIER();                         // release buf[cur]
    cur ^= 1;
  }

  // epilogues
  {
    float linv = 1.f / lH;
#pragma unroll
    for (int r = 0; r < 4; ++r) {
      float ir = __shfl(linv, g * 4 + r);
      size_t row = bS + q0H + w * 16 + g * 4 + r;
#pragma unroll
      for (int dt = 0; dt < 4; ++dt)
        attb[row * D_ + h * 64 + dt * 16 + ln] = f2bf(oH[dt][r] * ir);
    }
  }
  {
    float linv = 1.f / lL;
#pragma unroll
    for (int r = 0; r < 4; ++r) {
      float ir = __shfl(linv, g * 4 + r);
      size_t row = bS + q0L + w * 16 + g * 4 + r;
#pragma unroll
      for (int dt = 0; dt < 4; ++dt)
        attb[row * D_ + h * 64 + dt * 16 + ln] = f2bf(oL[dt][r] * ir);
    }
  }
}

// ---------------------------------------------------------------------------
extern "C" void kernel_launch(void* const* d_in, const int* in_sizes, int n_in,
                              void* d_out, int out_size, void* d_ws, size_t ws_size,
                              hipStream_t stream) {
  (void)in_sizes; (void)n_in; (void)out_size; (void)ws_size;
  const float* x   = (const float*)d_in[0];
  const int*   pos = (const int*)d_in[1];
  const float* w   = (const float*)d_in[2];   // (3,H,DK,D)
  const float* wo  = (const float*)d_in[3];   // (D, H*DK)
  float* out = (float*)d_out;

  u16* qkvb = (u16*)d_ws;                        // [4096][3072]
  u16* Vt   = qkvb + (size_t)M_ * NQKV;          // [2][16][64][2048]
  u16* attb = Vt + (size_t)B_ * H_ * 64 * S_;    // [4096][1024]
  u16* xb   = attb + (size_t)M_ * D_;            // [4096][1024]
  u16* wb   = xb + (size_t)M_ * D_;              // [3072][1024]  (contiguous after xb)
  u16* wob  = wb + (size_t)NQKV * D_;            // [1024][1024]  (contiguous after wb)
  float2* cstab = (float2*)(wob + (size_t)D_ * D_);  // [2048][32]

  rope_cs_kernel<<<(S_ * 32) / 256, 256, 0, stream>>>(pos, cstab);

  cvt_all_kernel<<<(N4X + N4W + N4WO) / 256, 256, 0, stream>>>(x, w, wo, xb);

  gemm_nt_mfma<true, true><<<dim3(NQKV / 128, M_ / 128), 256, 0, stream>>>(
      xb, wb, qkvb, cstab, NQKV, D_);

  v_transpose_kernel<<<dim3(S_ / 64, H_, B_), 256, 0, stream>>>(qkvb, Vt);

  attn_mfma<<<dim3(8, H_, B_), 512, 0, stream>>>(qkvb, Vt, attb);

  gemm_small_mfma<<<dim3(D_ / 64, M_ / 64), 256, 0, stream>>>(
      attb, wob, out, D_, D_);
}

// Round 9
// 187.835 us; speedup vs baseline: 8.5737x; 1.0079x over previous
//
#include <hip/hip_runtime.h>
#include <hip/hip_bf16.h>
#include <math.h>

#define B_   2
#define S_   2048
#define D_   1024
#define H_   16
#define DK_  64
#define NQKV 3072
#define M_   (B_ * S_)

typedef unsigned short u16;
typedef unsigned int   u32;
typedef __attribute__((ext_vector_type(8))) short short8;   // 8 bf16 (MFMA A/B frag)
typedef __attribute__((ext_vector_type(4))) float f32x4;    // MFMA C/D frag
typedef __attribute__((ext_vector_type(4))) u16   u16x4;

typedef const __attribute__((address_space(1))) void* gvptr;
typedef __attribute__((address_space(3))) void* lvptr;

// combined scale: 1/sqrt(64) * log2(e), so scores are in exp2 units directly
#define QSCALE 0.18033688011f

#if __has_builtin(__builtin_amdgcn_exp2f)
#define EXP2F(x) __builtin_amdgcn_exp2f(x)
#else
#define EXP2F(x) __expf(0.69314718056f * (x))
#endif

__device__ __forceinline__ u16 f2bf(float f) {
  union { float f; u32 u; } v; v.f = f;
  u32 r = v.u + 0x7FFF + ((v.u >> 16) & 1);   // RN-even
  return (u16)(r >> 16);
}
__device__ __forceinline__ float bf2f(u16 h) {
  union { u32 u; float f; } v; v.u = ((u32)h) << 16;
  return v.f;
}
__device__ __forceinline__ u32 cvtpk_bf16(float lo, float hi) {
  u32 r;
  asm("v_cvt_pk_bf16_f32 %0, %1, %2" : "=v"(r) : "v"(lo), "v"(hi));
  return r;
}

#define MEMFENCE() asm volatile("" ::: "memory")
#define RAW_BARRIER() do { MEMFENCE(); __builtin_amdgcn_s_barrier(); MEMFENCE(); } while (0)

// 8-slot row swizzle (128B rows: K tiles, GEMM tiles)
#define SWZ(r) ((((r) & 7) ^ ((((r) >> 3) & 1) << 2)))

// ---------------- merged f32->bf16 convert for x,w,wo + RoPE table ----------
#define N4X (M_ * D_ / 4)       // 1048576
#define N4W (NQKV * D_ / 4)     //  786432
#define N4WO (D_ * D_ / 4)      //  262144
#define NCVT (N4X + N4W + N4WO) // 2097152 (8192 blocks); +256 blocks rope
__global__ void cvt_all_kernel(const float* __restrict__ x,
                               const float* __restrict__ w,
                               const float* __restrict__ wo,
                               u16* __restrict__ dst,
                               const int* __restrict__ pos,
                               float2* __restrict__ cs) {
  int i = blockIdx.x * 256 + threadIdx.x;
  if (i < NCVT) {
    float4 v;
    if (i < N4X)            v = ((const float4*)x)[i];
    else if (i < N4X + N4W) v = ((const float4*)w)[i - N4X];
    else                    v = ((const float4*)wo)[i - (N4X + N4W)];
    u16x4 o;
    o[0] = f2bf(v.x); o[1] = f2bf(v.y); o[2] = f2bf(v.z); o[3] = f2bf(v.w);
    ((u16x4*)dst)[i] = o;
  } else {
    int idx = i - NCVT;           // 0 .. S*32-1
    int fi = idx & 31;
    int s = idx >> 5;
    double p = (double)pos[s];
    double t = p * pow(10000.0, -(double)fi / 32.0);
    cs[idx] = make_float2((float)cos(t), (float)sin(t));
  }
}

// ---------------- bf16 MFMA GEMM1 (m97 single-buffer), fused RoPE + Vt ------
// qkv = xb * wb^T. 128x128 tile, BK=64, 4 waves 2x2, 4x4 frags.
// Staging: global_load_lds 16B, linear LDS dest, inverse-swizzled SOURCE,
// XOR-swizzled ds_read (rule #21). Epilogue: q/k blocks (n0<2048) get RoPE
// and write qkvb; v blocks (n0>=2048) transpose via LDS (reusing As/Bs) and
// write Vt[b][h][dk][s] DIRECTLY — v_transpose kernel eliminated.
__global__ __launch_bounds__(256) void gemm_qkv_mfma(const u16* __restrict__ A,
                                                     const u16* __restrict__ Bm,
                                                     u16* __restrict__ qkvb,
                                                     u16* __restrict__ Vt,
                                                     const float2* __restrict__ cstab) {
  __shared__ u16 lds[2 * 128 * 64];
  u16* Asp = lds;                 // [128 rows][8 slots of 8]
  u16* Bsp = lds + 128 * 64;
  const int t  = threadIdx.x;
  const int w  = t >> 6, l = t & 63;
  const int g  = l >> 4, ln = l & 15;
  const int wm = w >> 1, wn = w & 1;
  const int m0 = blockIdx.y * 128, n0 = blockIdx.x * 128;
  const int Kd = D_, Nd = NQKV;

  const f32x4 vzero = {0.f, 0.f, 0.f, 0.f};
  f32x4 acc[4][4];
#pragma unroll
  for (int i = 0; i < 4; ++i)
#pragma unroll
    for (int j = 0; j < 4; ++j) acc[i][j] = vzero;

  for (int k0 = 0; k0 < Kd; k0 += 64) {
    __syncthreads();   // previous iteration's frag reads complete
#pragma unroll
    for (int p = 0; p < 4; ++p) {
      int c = p * 256 + t;
      int r = c >> 3, sx = (c & 7) ^ (r & 7);
      __builtin_amdgcn_global_load_lds(
          (gvptr)(A + (size_t)(m0 + r) * Kd + k0 + sx * 8),
          (lvptr)(&Asp[(p * 256 + w * 64) * 8]), 16, 0, 0);
      __builtin_amdgcn_global_load_lds(
          (gvptr)(Bm + (size_t)(n0 + r) * Kd + k0 + sx * 8),
          (lvptr)(&Bsp[(p * 256 + w * 64) * 8]), 16, 0, 0);
    }
    __syncthreads();   // drains vmcnt(0): LDS ready

#pragma unroll
    for (int ks = 0; ks < 2; ++ks) {
      short8 af[4], bf[4];
#pragma unroll
      for (int i = 0; i < 4; ++i) {
        int ra = wm * 64 + i * 16 + ln;
        af[i] = *(const short8*)&Asp[ra * 64 + (((ks * 4 + g) ^ (ra & 7)) * 8)];
        int rb = wn * 64 + i * 16 + ln;
        bf[i] = *(const short8*)&Bsp[rb * 64 + (((ks * 4 + g) ^ (rb & 7)) * 8)];
      }
#pragma unroll
      for (int i = 0; i < 4; ++i)
#pragma unroll
        for (int j = 0; j < 4; ++j)
          acc[i][j] = __builtin_amdgcn_mfma_f32_16x16x32_bf16(af[i], bf[j], acc[i][j], 0, 0, 0);
    }
  }

  if (n0 < 2048) {
    // q/k block: RoPE rotate pairs (even/odd cols), write qkvb
#pragma unroll
    for (int i = 0; i < 4; ++i)
#pragma unroll
      for (int r = 0; r < 4; ++r) {
        int rowi = m0 + wm * 64 + i * 16 + g * 4 + r;
        int srow = rowi & (S_ - 1);
#pragma unroll
        for (int j = 0; j < 4; ++j) {
          int dk = j * 16 + ln;
          float2 cs = cstab[srow * 32 + (dk >> 1)];
          float v = acc[i][j][r];
          float p = __shfl_xor(v, 1);
          float sn = (ln & 1) ? cs.y : -cs.y;
          float rot = fmaf(p, sn, v * cs.x);
          qkvb[(size_t)rowi * Nd + n0 + wn * 64 + j * 16 + ln] = f2bf(rot);
        }
      }
  } else {
    // v block: LDS transpose (reuse staging LDS) -> write Vt[b][h][dk][s]
    __syncthreads();               // all waves done reading Asp/Bsp
    u16* tr = lds;                 // [col 0..127][row 0..127], row XOR-swizzled
#pragma unroll
    for (int i = 0; i < 4; ++i)
#pragma unroll
      for (int j = 0; j < 4; ++j) {
        int col = wn * 64 + j * 16 + ln;
        int rowb = wm * 64 + i * 16 + g * 4;
#pragma unroll
        for (int r = 0; r < 4; ++r)
          tr[col * 128 + ((rowb + r) ^ ((col & 7) << 3))] = f2bf(acc[i][j][r]);
      }
    __syncthreads();
    {
      int col = t >> 1, half = t & 1;          // 128 cols x 2 halves
      int hh = ((n0 - 2048) >> 6) + (col >> 6);
      int dk = col & 63;
      int bb = m0 >> 11, sb = m0 & 2047;
      u16* dstp = Vt + ((size_t)(bb * H_ + hh) * 64 + dk) * S_ + sb + half * 64;
      const u16* srcp = tr + col * 128 + half * 64;
      int p7 = col & 7;
#pragma unroll
      for (int q = 0; q < 8; ++q)
        *(uint4*)(dstp + q * 8) = *(const uint4*)(srcp + ((q ^ p7) * 8));
    }
  }
}

// ---------------- bf16 MFMA GEMM 64x64 (GEMM2): 1024 blocks = 4/CU ----------
__global__ __launch_bounds__(256) void gemm_small_mfma(const u16* __restrict__ A,
                                                       const u16* __restrict__ Bm,
                                                       float* __restrict__ C,
                                                       int Nd, int Kd) {
  __shared__ u16 As[2][64 * 64];
  __shared__ u16 Bs[2][64 * 64];
  const int t  = threadIdx.x;
  const int w  = t >> 6, l = t & 63;
  const int g  = l >> 4, ln = l & 15;
  const int wm = w >> 1, wn = w & 1;
  const int m0 = blockIdx.y * 64, n0 = blockIdx.x * 64;

  auto stage = [&](int buf, int k0) {
#pragma unroll
    for (int p = 0; p < 2; ++p) {
      int c = p * 256 + t;
      int r = c >> 3;
      int sx = (c & 7) ^ (r & 7);
      __builtin_amdgcn_global_load_lds(
          (gvptr)(A + (size_t)(m0 + r) * Kd + k0 + sx * 8),
          (lvptr)(&As[buf][(p * 256 + w * 64) * 8]), 16, 0, 0);
      __builtin_amdgcn_global_load_lds(
          (gvptr)(Bm + (size_t)(n0 + r) * Kd + k0 + sx * 8),
          (lvptr)(&Bs[buf][(p * 256 + w * 64) * 8]), 16, 0, 0);
    }
  };

  const f32x4 vzero = {0.f, 0.f, 0.f, 0.f};
  f32x4 acc[2][2];
#pragma unroll
  for (int i = 0; i < 2; ++i)
#pragma unroll
    for (int j = 0; j < 2; ++j) acc[i][j] = vzero;

  const int nkt = Kd >> 6;
  stage(0, 0);
  int cur = 0;
#pragma unroll 1
  for (int kt = 0; kt < nkt; ++kt) {
    if (kt + 1 < nkt) {
      stage(cur ^ 1, (kt + 1) * 64);       // 4 loads/thread in flight
      asm volatile("s_waitcnt vmcnt(4)" ::: "memory");
    } else {
      asm volatile("s_waitcnt vmcnt(0)" ::: "memory");
    }
    RAW_BARRIER();

    __builtin_amdgcn_s_setprio(1);
#pragma unroll
    for (int ks = 0; ks < 2; ++ks) {
      short8 af[2], bf[2];
#pragma unroll
      for (int i = 0; i < 2; ++i) {
        int ra = wm * 32 + i * 16 + ln;
        af[i] = *(const short8*)&As[cur][ra * 64 + (((ks * 4 + g) ^ (ra & 7)) * 8)];
        int rb = wn * 32 + i * 16 + ln;
        bf[i] = *(const short8*)&Bs[cur][rb * 64 + (((ks * 4 + g) ^ (rb & 7)) * 8)];
      }
#pragma unroll
      for (int i = 0; i < 2; ++i)
#pragma unroll
        for (int j = 0; j < 2; ++j)
          acc[i][j] = __builtin_amdgcn_mfma_f32_16x16x32_bf16(af[i], bf[j], acc[i][j], 0, 0, 0);
    }
    __builtin_amdgcn_s_setprio(0);

    asm volatile("s_waitcnt lgkmcnt(0)" ::: "memory");
    RAW_BARRIER();
    cur ^= 1;
  }

#pragma unroll
  for (int i = 0; i < 2; ++i)
#pragma unroll
    for (int j = 0; j < 2; ++j)
#pragma unroll
      for (int r = 0; r < 4; ++r)
        C[(size_t)(m0 + wm * 32 + i * 16 + g * 4 + r) * Nd + n0 + wn * 32 + j * 16 + ln]
            = acc[i][j][r];
}

// ---------------- flash attention: merged-pair single KV pass, KVBLK=128 ----
// Block = q-tiles {15-bx (heavy), bx (light)} of one (b,h); ONE pass over the
// heavy tile's KV range; each staged 128-key tile feeds BOTH chains (light
// skips tiles beyond its diagonal). Uniform 17 chain-steps/block. K rows 128B
// use 8-slot XOR swizzle; V rows 256B use 16-slot XOR swizzle.
__global__ __launch_bounds__(512) void attn_mfma(const u16* __restrict__ qkvb,
                                                 const u16* __restrict__ Vt,
                                                 u16* __restrict__ attb) {
  __shared__ u16 Ks[2][128 * 64];   // [key][dk]
  __shared__ u16 Vs[2][64 * 128];   // [dk][key]
  const int t = threadIdx.x;
  const int w = t >> 6, l = t & 63;
  const int g = l >> 4, ln = l & 15;
  const int bx = blockIdx.x, h = blockIdx.y, b = blockIdx.z;
  const size_t bS = (size_t)b * S_;
  const u16* Kbase = qkvb + bS * NQKV + D_ + h * 64;          // row stride NQKV
  const u16* Vbase = Vt + (size_t)(b * H_ + h) * 64 * S_;     // row stride S_

  auto stage = [&](int buf, int k0) {
#pragma unroll
    for (int p = 0; p < 2; ++p) {
      int ck = p * 512 + t;                 // K chunk 0..1023
      int rk = ck >> 3, sk = (ck & 7) ^ SWZ(rk);
      __builtin_amdgcn_global_load_lds(
          (gvptr)(Kbase + (size_t)(k0 + rk) * NQKV + sk * 8),
          (lvptr)(&Ks[buf][(p * 512 + w * 64) * 8]), 16, 0, 0);
      int cv = p * 512 + t;                 // V chunk 0..1023
      int rv = cv >> 4, sv = (cv & 15) ^ (rv & 15);
      __builtin_amdgcn_global_load_lds(
          (gvptr)(Vbase + (size_t)rv * S_ + k0 + sv * 8),
          (lvptr)(&Vs[buf][(p * 512 + w * 64) * 8]), 16, 0, 0);
    }
  };

  const f32x4 vzero = {0.f, 0.f, 0.f, 0.f};

  const int tqH = 15 - bx, tqL = bx;
  const int q0H = tqH * 128, q0L = tqL * 128;
  const int nt = 16 - bx;                   // heavy pass length (128-key tiles)
  const int ntL = bx + 1;                   // light active tiles
  const int qgH = q0H + w * 16 + ln;
  const int qgL = q0L + w * 16 + ln;

  short8 qfH[2], qfL[2];
  {
    const u16* qr = qkvb + (bS + q0H + w * 16 + ln) * NQKV + h * 64;
    qfH[0] = *(const short8*)(qr + g * 8);
    qfH[1] = *(const short8*)(qr + 32 + g * 8);
    qr = qkvb + (bS + q0L + w * 16 + ln) * NQKV + h * 64;
    qfL[0] = *(const short8*)(qr + g * 8);
    qfL[1] = *(const short8*)(qr + 32 + g * 8);
#pragma unroll
    for (int kx = 0; kx < 2; ++kx)
#pragma unroll
      for (int e = 0; e < 8; ++e) {
        qfH[kx][e] = (short)f2bf(bf2f((u16)qfH[kx][e]) * QSCALE);
        qfL[kx][e] = (short)f2bf(bf2f((u16)qfL[kx][e]) * QSCALE);
      }
  }

  f32x4 oH[4], oL[4];
#pragma unroll
  for (int dt = 0; dt < 4; ++dt) { oH[dt] = vzero; oL[dt] = vzero; }
  float mH = -INFINITY, lH = 0.f, mL = -INFINITY, lL = 0.f;

  // one chain step: QK(16 MFMA) -> online SM -> pack -> PV(16 MFMA)
  auto chain = [&](const short8* qf, f32x4* o, float& mrun, float& lrun,
                   int qg, bool maskTile, int k0, int cur) {
    f32x4 sacc[8];
#pragma unroll
    for (int st = 0; st < 8; ++st) sacc[st] = vzero;
    __builtin_amdgcn_s_setprio(1);
#pragma unroll
    for (int st = 0; st < 8; ++st) {
      const int pr = ((ln >> 2) << 3) + ((st & 1) << 2) + (ln & 3) + ((st >> 1) << 5);
#pragma unroll
      for (int ks = 0; ks < 2; ++ks) {
        short8 kf = *(const short8*)&Ks[cur][pr * 64 + (((ks * 4 + g) ^ SWZ(pr)) * 8)];
        sacc[st] = __builtin_amdgcn_mfma_f32_16x16x32_bf16(kf, qf[ks], sacc[st], 0, 0, 0);
      }
    }
    __builtin_amdgcn_s_setprio(0);

    float tmax = -INFINITY;
    if (maskTile) {
#pragma unroll
      for (int st = 0; st < 8; ++st)
#pragma unroll
        for (int r = 0; r < 4; ++r) {
          int key = k0 + g * 8 + ((st & 1) << 2) + r + ((st >> 1) << 5);
          if (key > qg) sacc[st][r] = -INFINITY;
          tmax = fmaxf(tmax, sacc[st][r]);
        }
    } else {
#pragma unroll
      for (int st = 0; st < 8; ++st)
#pragma unroll
        for (int r = 0; r < 4; ++r) tmax = fmaxf(tmax, sacc[st][r]);
    }
    tmax = fmaxf(tmax, __shfl_xor(tmax, 16));
    tmax = fmaxf(tmax, __shfl_xor(tmax, 32));
    float al = 1.f, mnew = mrun;
    if (!__all(tmax <= mrun + 8.0f)) {       // defer-max (THR=8 in log2 units)
      mnew = fmaxf(mrun, tmax);
      al = EXP2F(mrun - mnew);
#pragma unroll
      for (int r = 0; r < 4; ++r) {
        float srs = __shfl(al, g * 4 + r);
#pragma unroll
        for (int dt = 0; dt < 4; ++dt) o[dt][r] *= srs;
      }
    }
    float lsum = 0.f;
#pragma unroll
    for (int st = 0; st < 8; ++st)
#pragma unroll
      for (int r = 0; r < 4; ++r) {
        float pe = EXP2F(sacc[st][r] - mnew);
        sacc[st][r] = pe;
        lsum += pe;
      }
    lsum += __shfl_xor(lsum, 16);
    lsum += __shfl_xor(lsum, 32);
    lrun = lrun * al + lsum;
    mrun = mnew;

    union { u32 u[4]; short8 v; } pa[4];
#pragma unroll
    for (int ks = 0; ks < 4; ++ks) {
      pa[ks].u[0] = cvtpk_bf16(sacc[2 * ks][0], sacc[2 * ks][1]);
      pa[ks].u[1] = cvtpk_bf16(sacc[2 * ks][2], sacc[2 * ks][3]);
      pa[ks].u[2] = cvtpk_bf16(sacc[2 * ks + 1][0], sacc[2 * ks + 1][1]);
      pa[ks].u[3] = cvtpk_bf16(sacc[2 * ks + 1][2], sacc[2 * ks + 1][3]);
    }

    __builtin_amdgcn_s_setprio(1);
#pragma unroll
    for (int ks = 0; ks < 4; ++ks)
#pragma unroll
      for (int dt = 0; dt < 4; ++dt) {
        const int dr = dt * 16 + ln;
        short8 vf = *(const short8*)&Vs[cur][dr * 128 + (((ks * 4 + g) ^ (dr & 15)) * 8)];
        o[dt] = __builtin_amdgcn_mfma_f32_16x16x32_bf16(pa[ks].v, vf, o[dt], 0, 0, 0);
      }
    __builtin_amdgcn_s_setprio(0);
  };

  stage(0, 0);
  int cur = 0;
#pragma unroll 1
  for (int kt = 0; kt < nt; ++kt) {
    const int k0 = kt * 128;
    if (kt + 1 < nt) {
      stage(cur ^ 1, k0 + 128);            // 4 loads/thread in flight
      asm volatile("s_waitcnt vmcnt(4)" ::: "memory");
    } else {
      asm volatile("s_waitcnt vmcnt(0)" ::: "memory");
    }
    RAW_BARRIER();                         // buf[cur] staged

    chain(qfH, oH, mH, lH, qgH, kt == nt - 1, k0, cur);
    if (kt < ntL)
      chain(qfL, oL, mL, lL, qgL, kt == tqL, k0, cur);

    asm volatile("s_waitcnt lgkmcnt(0)" ::: "memory");
    RAW_BARRIER();                         // release buf[cur]
    cur ^= 1;
  }

  // epilogues
  {
    float linv = 1.f / lH;
#pragma unroll
    for (int r = 0; r < 4; ++r) {
      float ir = __shfl(linv, g * 4 + r);
      size_t row = bS + q0H + w * 16 + g * 4 + r;
#pragma unroll
      for (int dt = 0; dt < 4; ++dt)
        attb[row * D_ + h * 64 + dt * 16 + ln] = f2bf(oH[dt][r] * ir);
    }
  }
  {
    float linv = 1.f / lL;
#pragma unroll
    for (int r = 0; r < 4; ++r) {
      float ir = __shfl(linv, g * 4 + r);
      size_t row = bS + q0L + w * 16 + g * 4 + r;
#pragma unroll
      for (int dt = 0; dt < 4; ++dt)
        attb[row * D_ + h * 64 + dt * 16 + ln] = f2bf(oL[dt][r] * ir);
    }
  }
}

// ---------------------------------------------------------------------------
extern "C" void kernel_launch(void* const* d_in, const int* in_sizes, int n_in,
                              void* d_out, int out_size, void* d_ws, size_t ws_size,
                              hipStream_t stream) {
  (void)in_sizes; (void)n_in; (void)out_size; (void)ws_size;
  const float* x   = (const float*)d_in[0];
  const int*   pos = (const int*)d_in[1];
  const float* w   = (const float*)d_in[2];   // (3,H,DK,D)
  const float* wo  = (const float*)d_in[3];   // (D, H*DK)
  float* out = (float*)d_out;

  u16* qkvb = (u16*)d_ws;                        // [4096][3072] (v-part unused)
  u16* Vt   = qkvb + (size_t)M_ * NQKV;          // [2][16][64][2048]
  u16* attb = Vt + (size_t)B_ * H_ * 64 * S_;    // [4096][1024]
  u16* xb   = attb + (size_t)M_ * D_;            // [4096][1024]
  u16* wb   = xb + (size_t)M_ * D_;              // [3072][1024]  (contiguous after xb)
  u16* wob  = wb + (size_t)NQKV * D_;            // [1024][1024]  (contiguous after wb)
  float2* cstab = (float2*)(wob + (size_t)D_ * D_);  // [2048][32]

  cvt_all_kernel<<<NCVT / 256 + 256, 256, 0, stream>>>(x, w, wo, xb, pos, cstab);

  gemm_qkv_mfma<<<dim3(NQKV / 128, M_ / 128), 256, 0, stream>>>(
      xb, wb, qkvb, Vt, cstab);

  attn_mfma<<<dim3(8, H_, B_), 512, 0, stream>>>(qkvb, Vt, attb);

  gemm_small_mfma<<<dim3(D_ / 64, M_ / 64), 256, 0, stream>>>(
      attb, wob, out, D_, D_);
}

// Round 11
// 185.653 us; speedup vs baseline: 8.6745x; 1.0118x over previous
//
#include <hip/hip_runtime.h>
#include <hip/hip_bf16.h>
#include <math.h>

#define B_   2
#define S_   2048
#define D_   1024
#define H_   16
#define DK_  64
#define NQKV 3072
#define M_   (B_ * S_)

typedef unsigned short u16;
typedef unsigned int   u32;
typedef __attribute__((ext_vector_type(8))) short short8;   // 8 bf16 (MFMA A/B frag)
typedef __attribute__((ext_vector_type(4))) float f32x4;    // MFMA C/D frag
typedef __attribute__((ext_vector_type(4))) u16   u16x4;

typedef const __attribute__((address_space(1))) void* gvptr;
typedef __attribute__((address_space(3))) void* lvptr;

// combined scale: 1/sqrt(64) * log2(e), so scores are in exp2 units directly
#define QSCALE 0.18033688011f

#if __has_builtin(__builtin_amdgcn_exp2f)
#define EXP2F(x) __builtin_amdgcn_exp2f(x)
#else
#define EXP2F(x) __expf(0.69314718056f * (x))
#endif

__device__ __forceinline__ u16 f2bf(float f) {
  union { float f; u32 u; } v; v.f = f;
  u32 r = v.u + 0x7FFF + ((v.u >> 16) & 1);   // RN-even
  return (u16)(r >> 16);
}
__device__ __forceinline__ float bf2f(u16 h) {
  union { u32 u; float f; } v; v.u = ((u32)h) << 16;
  return v.f;
}
__device__ __forceinline__ u32 cvtpk_bf16(float lo, float hi) {
  u32 r;
  asm("v_cvt_pk_bf16_f32 %0, %1, %2" : "=v"(r) : "v"(lo), "v"(hi));
  return r;
}

#define MEMFENCE() asm volatile("" ::: "memory")
#define RAW_BARRIER() do { MEMFENCE(); __builtin_amdgcn_s_barrier(); MEMFENCE(); } while (0)

// 8-slot row swizzle (128B rows: K tiles, GEMM tiles)
#define SWZ(r) ((((r) & 7) ^ ((((r) >> 3) & 1) << 2)))

// ---------------- merged f32->bf16 convert for x,w,wo + RoPE table ----------
#define N4X (M_ * D_ / 4)       // 1048576
#define N4W (NQKV * D_ / 4)     //  786432
#define N4WO (D_ * D_ / 4)      //  262144
#define NCVT (N4X + N4W + N4WO) // 2097152 (8192 blocks); +256 blocks rope
__global__ void cvt_all_kernel(const float* __restrict__ x,
                               const float* __restrict__ w,
                               const float* __restrict__ wo,
                               u16* __restrict__ dst,
                               const int* __restrict__ pos,
                               float2* __restrict__ cs) {
  int i = blockIdx.x * 256 + threadIdx.x;
  if (i < NCVT) {
    float4 v;
    if (i < N4X)            v = ((const float4*)x)[i];
    else if (i < N4X + N4W) v = ((const float4*)w)[i - N4X];
    else                    v = ((const float4*)wo)[i - (N4X + N4W)];
    u16x4 o;
    o[0] = f2bf(v.x); o[1] = f2bf(v.y); o[2] = f2bf(v.z); o[3] = f2bf(v.w);
    ((u16x4*)dst)[i] = o;
  } else {
    int idx = i - NCVT;           // 0 .. S*32-1
    int fi = idx & 31;
    int s = idx >> 5;
    double p = (double)pos[s];
    double t = p * pow(10000.0, -(double)fi / 32.0);
    cs[idx] = make_float2((float)cos(t), (float)sin(t));
  }
}

// ---------------- bf16 MFMA GEMM1 (m97 single-buffer), fused RoPE + Vt ------
__global__ __launch_bounds__(256) void gemm_qkv_mfma(const u16* __restrict__ A,
                                                     const u16* __restrict__ Bm,
                                                     u16* __restrict__ qkvb,
                                                     u16* __restrict__ Vt,
                                                     const float2* __restrict__ cstab) {
  __shared__ u16 lds[2 * 128 * 64];
  u16* Asp = lds;                 // [128 rows][8 slots of 8]
  u16* Bsp = lds + 128 * 64;
  const int t  = threadIdx.x;
  const int w  = t >> 6, l = t & 63;
  const int g  = l >> 4, ln = l & 15;
  const int wm = w >> 1, wn = w & 1;
  const int m0 = blockIdx.y * 128, n0 = blockIdx.x * 128;
  const int Kd = D_, Nd = NQKV;

  const f32x4 vzero = {0.f, 0.f, 0.f, 0.f};
  f32x4 acc[4][4];
#pragma unroll
  for (int i = 0; i < 4; ++i)
#pragma unroll
    for (int j = 0; j < 4; ++j) acc[i][j] = vzero;

  for (int k0 = 0; k0 < Kd; k0 += 64) {
    __syncthreads();   // previous iteration's frag reads complete
#pragma unroll
    for (int p = 0; p < 4; ++p) {
      int c = p * 256 + t;
      int r = c >> 3, sx = (c & 7) ^ (r & 7);
      __builtin_amdgcn_global_load_lds(
          (gvptr)(A + (size_t)(m0 + r) * Kd + k0 + sx * 8),
          (lvptr)(&Asp[(p * 256 + w * 64) * 8]), 16, 0, 0);
      __builtin_amdgcn_global_load_lds(
          (gvptr)(Bm + (size_t)(n0 + r) * Kd + k0 + sx * 8),
          (lvptr)(&Bsp[(p * 256 + w * 64) * 8]), 16, 0, 0);
    }
    __syncthreads();   // drains vmcnt(0): LDS ready

#pragma unroll
    for (int ks = 0; ks < 2; ++ks) {
      short8 af[4], bf[4];
#pragma unroll
      for (int i = 0; i < 4; ++i) {
        int ra = wm * 64 + i * 16 + ln;
        af[i] = *(const short8*)&Asp[ra * 64 + (((ks * 4 + g) ^ (ra & 7)) * 8)];
        int rb = wn * 64 + i * 16 + ln;
        bf[i] = *(const short8*)&Bsp[rb * 64 + (((ks * 4 + g) ^ (rb & 7)) * 8)];
      }
#pragma unroll
      for (int i = 0; i < 4; ++i)
#pragma unroll
        for (int j = 0; j < 4; ++j)
          acc[i][j] = __builtin_amdgcn_mfma_f32_16x16x32_bf16(af[i], bf[j], acc[i][j], 0, 0, 0);
    }
  }

  if (n0 < 2048) {
    // q/k block: RoPE rotate pairs (even/odd cols), write qkvb
#pragma unroll
    for (int i = 0; i < 4; ++i)
#pragma unroll
      for (int r = 0; r < 4; ++r) {
        int rowi = m0 + wm * 64 + i * 16 + g * 4 + r;
        int srow = rowi & (S_ - 1);
#pragma unroll
        for (int j = 0; j < 4; ++j) {
          int dk = j * 16 + ln;
          float2 cs = cstab[srow * 32 + (dk >> 1)];
          float v = acc[i][j][r];
          float p = __shfl_xor(v, 1);
          float sn = (ln & 1) ? cs.y : -cs.y;
          float rot = fmaf(p, sn, v * cs.x);
          qkvb[(size_t)rowi * Nd + n0 + wn * 64 + j * 16 + ln] = f2bf(rot);
        }
      }
  } else {
    // v block: LDS transpose (reuse staging LDS) -> write Vt[b][h][dk][s]
    __syncthreads();               // all waves done reading Asp/Bsp
    u16* tr = lds;                 // [col 0..127][row 0..127], row XOR-swizzled
#pragma unroll
    for (int i = 0; i < 4; ++i)
#pragma unroll
      for (int j = 0; j < 4; ++j) {
        int col = wn * 64 + j * 16 + ln;
        int rowb = wm * 64 + i * 16 + g * 4;
#pragma unroll
        for (int r = 0; r < 4; ++r)
          tr[col * 128 + ((rowb + r) ^ ((col & 7) << 3))] = f2bf(acc[i][j][r]);
      }
    __syncthreads();
    {
      int col = t >> 1, half = t & 1;          // 128 cols x 2 halves
      int hh = ((n0 - 2048) >> 6) + (col >> 6);
      int dk = col & 63;
      int bb = m0 >> 11, sb = m0 & 2047;
      u16* dstp = Vt + ((size_t)(bb * H_ + hh) * 64 + dk) * S_ + sb + half * 64;
      const u16* srcp = tr + col * 128 + half * 64;
      int p7 = col & 7;
#pragma unroll
      for (int q = 0; q < 8; ++q)
        *(uint4*)(dstp + q * 8) = *(const uint4*)(srcp + ((q ^ p7) * 8));
    }
  }
}

// ---------------- bf16 MFMA GEMM 64x64 (GEMM2): 1024 blocks = 4/CU ----------
__global__ __launch_bounds__(256) void gemm_small_mfma(const u16* __restrict__ A,
                                                       const u16* __restrict__ Bm,
                                                       float* __restrict__ C,
                                                       int Nd, int Kd) {
  __shared__ u16 As[2][64 * 64];
  __shared__ u16 Bs[2][64 * 64];
  const int t  = threadIdx.x;
  const int w  = t >> 6, l = t & 63;
  const int g  = l >> 4, ln = l & 15;
  const int wm = w >> 1, wn = w & 1;
  const int m0 = blockIdx.y * 64, n0 = blockIdx.x * 64;

  auto stage = [&](int buf, int k0) {
#pragma unroll
    for (int p = 0; p < 2; ++p) {
      int c = p * 256 + t;
      int r = c >> 3;
      int sx = (c & 7) ^ (r & 7);
      __builtin_amdgcn_global_load_lds(
          (gvptr)(A + (size_t)(m0 + r) * Kd + k0 + sx * 8),
          (lvptr)(&As[buf][(p * 256 + w * 64) * 8]), 16, 0, 0);
      __builtin_amdgcn_global_load_lds(
          (gvptr)(Bm + (size_t)(n0 + r) * Kd + k0 + sx * 8),
          (lvptr)(&Bs[buf][(p * 256 + w * 64) * 8]), 16, 0, 0);
    }
  };

  const f32x4 vzero = {0.f, 0.f, 0.f, 0.f};
  f32x4 acc[2][2];
#pragma unroll
  for (int i = 0; i < 2; ++i)
#pragma unroll
    for (int j = 0; j < 2; ++j) acc[i][j] = vzero;

  const int nkt = Kd >> 6;
  stage(0, 0);
  int cur = 0;
#pragma unroll 1
  for (int kt = 0; kt < nkt; ++kt) {
    if (kt + 1 < nkt) {
      stage(cur ^ 1, (kt + 1) * 64);       // 4 loads/thread in flight
      asm volatile("s_waitcnt vmcnt(4)" ::: "memory");
    } else {
      asm volatile("s_waitcnt vmcnt(0)" ::: "memory");
    }
    RAW_BARRIER();

    __builtin_amdgcn_s_setprio(1);
#pragma unroll
    for (int ks = 0; ks < 2; ++ks) {
      short8 af[2], bf[2];
#pragma unroll
      for (int i = 0; i < 2; ++i) {
        int ra = wm * 32 + i * 16 + ln;
        af[i] = *(const short8*)&As[cur][ra * 64 + (((ks * 4 + g) ^ (ra & 7)) * 8)];
        int rb = wn * 32 + i * 16 + ln;
        bf[i] = *(const short8*)&Bs[cur][rb * 64 + (((ks * 4 + g) ^ (rb & 7)) * 8)];
      }
#pragma unroll
      for (int i = 0; i < 2; ++i)
#pragma unroll
        for (int j = 0; j < 2; ++j)
          acc[i][j] = __builtin_amdgcn_mfma_f32_16x16x32_bf16(af[i], bf[j], acc[i][j], 0, 0, 0);
    }
    __builtin_amdgcn_s_setprio(0);

    asm volatile("s_waitcnt lgkmcnt(0)" ::: "memory");
    RAW_BARRIER();
    cur ^= 1;
  }

#pragma unroll
  for (int i = 0; i < 2; ++i)
#pragma unroll
    for (int j = 0; j < 2; ++j)
#pragma unroll
      for (int r = 0; r < 4; ++r)
        C[(size_t)(m0 + wm * 32 + i * 16 + g * 4 + r) * Nd + n0 + wn * 32 + j * 16 + ln]
            = acc[i][j][r];
}

// ---------------- flash attention: merged-pair single KV pass, KVBLK=128 ----
// SINGLE change vs round-9 (known-pass): 1D grid 256, XCD co-location — all 8
// bx blocks of one (b,h) share id%8 -> same XCD -> K/V (512KB) fetched once
// into that XCD's 4MB L2. Chain internals byte-identical to round 9.
__global__ __launch_bounds__(512) void attn_mfma(const u16* __restrict__ qkvb,
                                                 const u16* __restrict__ Vt,
                                                 u16* __restrict__ attb) {
  __shared__ u16 Ks[2][128 * 64];   // [key][dk]
  __shared__ u16 Vs[2][64 * 128];   // [dk][key]
  const int t = threadIdx.x;
  const int w = t >> 6, l = t & 63;
  const int g = l >> 4, ln = l & 15;
  // XCD co-location: id = (bx*4 + (pair&3))*8 + (pair>>2); bijective inverse:
  const int id = blockIdx.x;
  const int xcd = id & 7, slot = id >> 3;     // slot 0..31
  const int pair = xcd * 4 + (slot & 3);      // 0..31 = b*16+h
  const int bx = slot >> 2;                   // 0..7
  const int b = pair >> 4, h = pair & 15;
  const size_t bS = (size_t)b * S_;
  const u16* Kbase = qkvb + bS * NQKV + D_ + h * 64;          // row stride NQKV
  const u16* Vbase = Vt + (size_t)(b * H_ + h) * 64 * S_;     // row stride S_

  auto stage = [&](int buf, int k0) {
#pragma unroll
    for (int p = 0; p < 2; ++p) {
      int ck = p * 512 + t;                 // K chunk 0..1023
      int rk = ck >> 3, sk = (ck & 7) ^ SWZ(rk);
      __builtin_amdgcn_global_load_lds(
          (gvptr)(Kbase + (size_t)(k0 + rk) * NQKV + sk * 8),
          (lvptr)(&Ks[buf][(p * 512 + w * 64) * 8]), 16, 0, 0);
      int cv = p * 512 + t;                 // V chunk 0..1023
      int rv = cv >> 4, sv = (cv & 15) ^ (rv & 15);
      __builtin_amdgcn_global_load_lds(
          (gvptr)(Vbase + (size_t)rv * S_ + k0 + sv * 8),
          (lvptr)(&Vs[buf][(p * 512 + w * 64) * 8]), 16, 0, 0);
    }
  };

  const f32x4 vzero = {0.f, 0.f, 0.f, 0.f};

  const int tqH = 15 - bx, tqL = bx;
  const int q0H = tqH * 128, q0L = tqL * 128;
  const int nt = 16 - bx;                   // heavy pass length (128-key tiles)
  const int ntL = bx + 1;                   // light active tiles
  const int qgH = q0H + w * 16 + ln;
  const int qgL = q0L + w * 16 + ln;

  short8 qfH[2], qfL[2];
  {
    const u16* qr = qkvb + (bS + q0H + w * 16 + ln) * NQKV + h * 64;
    qfH[0] = *(const short8*)(qr + g * 8);
    qfH[1] = *(const short8*)(qr + 32 + g * 8);
    qr = qkvb + (bS + q0L + w * 16 + ln) * NQKV + h * 64;
    qfL[0] = *(const short8*)(qr + g * 8);
    qfL[1] = *(const short8*)(qr + 32 + g * 8);
#pragma unroll
    for (int kx = 0; kx < 2; ++kx)
#pragma unroll
      for (int e = 0; e < 8; ++e) {
        qfH[kx][e] = (short)f2bf(bf2f((u16)qfH[kx][e]) * QSCALE);
        qfL[kx][e] = (short)f2bf(bf2f((u16)qfL[kx][e]) * QSCALE);
      }
  }

  f32x4 oH[4], oL[4];
#pragma unroll
  for (int dt = 0; dt < 4; ++dt) { oH[dt] = vzero; oL[dt] = vzero; }
  float mH = -INFINITY, lH = 0.f, mL = -INFINITY, lL = 0.f;

  // one chain step: QK(16 MFMA) -> online SM -> pack -> PV(16 MFMA)
  auto chain = [&](const short8* qf, f32x4* o, float& mrun, float& lrun,
                   int qg, bool maskTile, int k0, int cur) {
    f32x4 sacc[8];
#pragma unroll
    for (int st = 0; st < 8; ++st) sacc[st] = vzero;
    __builtin_amdgcn_s_setprio(1);
#pragma unroll
    for (int st = 0; st < 8; ++st) {
      const int pr = ((ln >> 2) << 3) + ((st & 1) << 2) + (ln & 3) + ((st >> 1) << 5);
#pragma unroll
      for (int ks = 0; ks < 2; ++ks) {
        short8 kf = *(const short8*)&Ks[cur][pr * 64 + (((ks * 4 + g) ^ SWZ(pr)) * 8)];
        sacc[st] = __builtin_amdgcn_mfma_f32_16x16x32_bf16(kf, qf[ks], sacc[st], 0, 0, 0);
      }
    }
    __builtin_amdgcn_s_setprio(0);

    float tmax = -INFINITY;
    if (maskTile) {
#pragma unroll
      for (int st = 0; st < 8; ++st)
#pragma unroll
        for (int r = 0; r < 4; ++r) {
          int key = k0 + g * 8 + ((st & 1) << 2) + r + ((st >> 1) << 5);
          if (key > qg) sacc[st][r] = -INFINITY;
          tmax = fmaxf(tmax, sacc[st][r]);
        }
    } else {
#pragma unroll
      for (int st = 0; st < 8; ++st)
#pragma unroll
        for (int r = 0; r < 4; ++r) tmax = fmaxf(tmax, sacc[st][r]);
    }
    tmax = fmaxf(tmax, __shfl_xor(tmax, 16));
    tmax = fmaxf(tmax, __shfl_xor(tmax, 32));
    float al = 1.f, mnew = mrun;
    if (!__all(tmax <= mrun + 8.0f)) {       // defer-max (THR=8 in log2 units)
      mnew = fmaxf(mrun, tmax);
      al = EXP2F(mrun - mnew);
#pragma unroll
      for (int r = 0; r < 4; ++r) {
        float srs = __shfl(al, g * 4 + r);
#pragma unroll
        for (int dt = 0; dt < 4; ++dt) o[dt][r] *= srs;
      }
    }
    float lsum = 0.f;
#pragma unroll
    for (int st = 0; st < 8; ++st)
#pragma unroll
      for (int r = 0; r < 4; ++r) {
        float pe = EXP2F(sacc[st][r] - mnew);
        sacc[st][r] = pe;
        lsum += pe;
      }
    lsum += __shfl_xor(lsum, 16);
    lsum += __shfl_xor(lsum, 32);
    lrun = lrun * al + lsum;
    mrun = mnew;

    union { u32 u[4]; short8 v; } pa[4];
#pragma unroll
    for (int ks = 0; ks < 4; ++ks) {
      pa[ks].u[0] = cvtpk_bf16(sacc[2 * ks][0], sacc[2 * ks][1]);
      pa[ks].u[1] = cvtpk_bf16(sacc[2 * ks][2], sacc[2 * ks][3]);
      pa[ks].u[2] = cvtpk_bf16(sacc[2 * ks + 1][0], sacc[2 * ks + 1][1]);
      pa[ks].u[3] = cvtpk_bf16(sacc[2 * ks + 1][2], sacc[2 * ks + 1][3]);
    }

    __builtin_amdgcn_s_setprio(1);
#pragma unroll
    for (int ks = 0; ks < 4; ++ks)
#pragma unroll
      for (int dt = 0; dt < 4; ++dt) {
        const int dr = dt * 16 + ln;
        short8 vf = *(const short8*)&Vs[cur][dr * 128 + (((ks * 4 + g) ^ (dr & 15)) * 8)];
        o[dt] = __builtin_amdgcn_mfma_f32_16x16x32_bf16(pa[ks].v, vf, o[dt], 0, 0, 0);
      }
    __builtin_amdgcn_s_setprio(0);
  };

  stage(0, 0);
  int cur = 0;
#pragma unroll 1
  for (int kt = 0; kt < nt; ++kt) {
    const int k0 = kt * 128;
    if (kt + 1 < nt) {
      stage(cur ^ 1, k0 + 128);            // 4 loads/thread in flight
      asm volatile("s_waitcnt vmcnt(4)" ::: "memory");
    } else {
      asm volatile("s_waitcnt vmcnt(0)" ::: "memory");
    }
    RAW_BARRIER();                         // buf[cur] staged

    chain(qfH, oH, mH, lH, qgH, kt == nt - 1, k0, cur);
    if (kt < ntL)
      chain(qfL, oL, mL, lL, qgL, kt == tqL, k0, cur);

    asm volatile("s_waitcnt lgkmcnt(0)" ::: "memory");
    RAW_BARRIER();                         // release buf[cur]
    cur ^= 1;
  }

  // epilogues
  {
    float linv = 1.f / lH;
#pragma unroll
    for (int r = 0; r < 4; ++r) {
      float ir = __shfl(linv, g * 4 + r);
      size_t row = bS + q0H + w * 16 + g * 4 + r;
#pragma unroll
      for (int dt = 0; dt < 4; ++dt)
        attb[row * D_ + h * 64 + dt * 16 + ln] = f2bf(oH[dt][r] * ir);
    }
  }
  {
    float linv = 1.f / lL;
#pragma unroll
    for (int r = 0; r < 4; ++r) {
      float ir = __shfl(linv, g * 4 + r);
      size_t row = bS + q0L + w * 16 + g * 4 + r;
#pragma unroll
      for (int dt = 0; dt < 4; ++dt)
        attb[row * D_ + h * 64 + dt * 16 + ln] = f2bf(oL[dt][r] * ir);
    }
  }
}

// ---------------------------------------------------------------------------
extern "C" void kernel_launch(void* const* d_in, const int* in_sizes, int n_in,
                              void* d_out, int out_size, void* d_ws, size_t ws_size,
                              hipStream_t stream) {
  (void)in_sizes; (void)n_in; (void)out_size; (void)ws_size;
  const float* x   = (const float*)d_in[0];
  const int*   pos = (const int*)d_in[1];
  const float* w   = (const float*)d_in[2];   // (3,H,DK,D)
  const float* wo  = (const float*)d_in[3];   // (D, H*DK)
  float* out = (float*)d_out;

  u16* qkvb = (u16*)d_ws;                        // [4096][3072] (v-part unused)
  u16* Vt   = qkvb + (size_t)M_ * NQKV;          // [2][16][64][2048]
  u16* attb = Vt + (size_t)B_ * H_ * 64 * S_;    // [4096][1024]
  u16* xb   = attb + (size_t)M_ * D_;            // [4096][1024]
  u16* wb   = xb + (size_t)M_ * D_;              // [3072][1024]  (contiguous after xb)
  u16* wob  = wb + (size_t)NQKV * D_;            // [1024][1024]  (contiguous after wb)
  float2* cstab = (float2*)(wob + (size_t)D_ * D_);  // [2048][32]

  cvt_all_kernel<<<NCVT / 256 + 256, 256, 0, stream>>>(x, w, wo, xb, pos, cstab);

  gemm_qkv_mfma<<<dim3(NQKV / 128, M_ / 128), 256, 0, stream>>>(
      xb, wb, qkvb, Vt, cstab);

  attn_mfma<<<dim3(256), 512, 0, stream>>>(qkvb, Vt, attb);

  gemm_small_mfma<<<dim3(D_ / 64, M_ / 64), 256, 0, stream>>>(
      attb, wob, out, D_, D_);
}

// Round 12
// 178.482 us; speedup vs baseline: 9.0230x; 1.0402x over previous
//
#include <hip/hip_runtime.h>
#include <hip/hip_bf16.h>
#include <math.h>

#define B_   2
#define S_   2048
#define D_   1024
#define H_   16
#define DK_  64
#define NQKV 3072
#define M_   (B_ * S_)

typedef unsigned short u16;
typedef unsigned int   u32;
typedef __attribute__((ext_vector_type(8))) short short8;   // 8 bf16 (MFMA A/B frag)
typedef __attribute__((ext_vector_type(4))) float f32x4;    // MFMA C/D frag
typedef __attribute__((ext_vector_type(4))) u16   u16x4;

typedef const __attribute__((address_space(1))) void* gvptr;
typedef __attribute__((address_space(3))) void* lvptr;

// combined scale: 1/sqrt(64) * log2(e), so scores are in exp2 units directly
#define QSCALE 0.18033688011f

#if __has_builtin(__builtin_amdgcn_exp2f)
#define EXP2F(x) __builtin_amdgcn_exp2f(x)
#else
#define EXP2F(x) __expf(0.69314718056f * (x))
#endif

__device__ __forceinline__ u16 f2bf(float f) {
  union { float f; u32 u; } v; v.f = f;
  u32 r = v.u + 0x7FFF + ((v.u >> 16) & 1);   // RN-even
  return (u16)(r >> 16);
}
__device__ __forceinline__ float bf2f(u16 h) {
  union { u32 u; float f; } v; v.u = ((u32)h) << 16;
  return v.f;
}
__device__ __forceinline__ u32 cvtpk_bf16(float lo, float hi) {
  u32 r;
  asm("v_cvt_pk_bf16_f32 %0, %1, %2" : "=v"(r) : "v"(lo), "v"(hi));
  return r;
}

#define MEMFENCE() asm volatile("" ::: "memory")
#define RAW_BARRIER() do { MEMFENCE(); __builtin_amdgcn_s_barrier(); MEMFENCE(); } while (0)

// 8-slot row swizzle (128B rows: K tiles, GEMM tiles)
#define SWZ(r) ((((r) & 7) ^ ((((r) >> 3) & 1) << 2)))

// ---------------- merged f32->bf16 convert for x,w,wo + RoPE table ----------
#define N4X (M_ * D_ / 4)       // 1048576
#define N4W (NQKV * D_ / 4)     //  786432
#define N4WO (D_ * D_ / 4)      //  262144
#define NCVT (N4X + N4W + N4WO) // 2097152 (8192 blocks); +256 blocks rope
__global__ void cvt_all_kernel(const float* __restrict__ x,
                               const float* __restrict__ w,
                               const float* __restrict__ wo,
                               u16* __restrict__ dst,
                               const int* __restrict__ pos,
                               float2* __restrict__ cs) {
  int i = blockIdx.x * 256 + threadIdx.x;
  if (i < NCVT) {
    float4 v;
    if (i < N4X)            v = ((const float4*)x)[i];
    else if (i < N4X + N4W) v = ((const float4*)w)[i - N4X];
    else                    v = ((const float4*)wo)[i - (N4X + N4W)];
    u16x4 o;
    o[0] = f2bf(v.x); o[1] = f2bf(v.y); o[2] = f2bf(v.z); o[3] = f2bf(v.w);
    ((u16x4*)dst)[i] = o;
  } else {
    int idx = i - NCVT;           // 0 .. S*32-1
    int fi = idx & 31;
    int s = idx >> 5;
    double p = (double)pos[s];
    double t = p * pow(10000.0, -(double)fi / 32.0);
    cs[idx] = make_float2((float)cos(t), (float)sin(t));
  }
}

// ---------------- bf16 MFMA GEMM1: 256x256 tile, 8 waves, counted-vmcnt -----
// qkv = xb * wb^T (M=4096, N=3072, K=1024). BK=64, dbuf (128KB LDS, 1 blk/CU).
// Rationale: GEMM1 is tile-read-BW bound (43MB FETCH = 3x unique; step time
// 4x MFMA issue). 256^2 halves aggregate tile traffic; XCD-chunked mapping
// (4M x 6N region/XCD -> A+B ~5MB in 4MB L2) localizes panel reuse. Handshake
// = round-8-verified dbuf: stage next slot, vmcnt(8) keeps them in flight,
// raw barriers, setprio on MFMA cluster. Epilogue: RoPE (n0<2048) or
// V-transpose to Vt (n0>=2048) via 256x256 LDS reuse.
__global__ __launch_bounds__(512) void gemm_qkv_mfma(const u16* __restrict__ A,
                                                     const u16* __restrict__ Bm,
                                                     u16* __restrict__ qkvb,
                                                     u16* __restrict__ Vt,
                                                     const float2* __restrict__ cstab) {
  __shared__ u16 lds[65536];      // 2 slots x (A 256x64 + B 256x64) = 128KB
  const int t  = threadIdx.x;
  const int w  = t >> 6, l = t & 63;
  const int g  = l >> 4, ln = l & 15;
  const int wm = w >> 2, wn = w & 3;           // 2M x 4N waves
  // XCD chunking: 16x12 tile grid; XCD region = 4M x 6N (24 blocks each)
  const int id = blockIdx.x;
  const int xcd = id & 7, s_ = id >> 3;        // s_ 0..23
  const int by = (xcd >> 1) * 4 + (s_ & 3);    // 0..15
  const int bx = (xcd & 1) * 6 + (s_ >> 2);    // 0..11
  const int m0 = by * 256, n0 = bx * 256;
  const int Kd = D_, Nd = NQKV;

  auto As = [&](int slot) { return lds + slot * 32768; };
  auto Bs = [&](int slot) { return lds + slot * 32768 + 16384; };

  auto stage = [&](int slot, int k0) {
#pragma unroll
    for (int p = 0; p < 4; ++p) {
      int c = p * 512 + t;
      int r = c >> 3, sx = (c & 7) ^ (r & 7);
      __builtin_amdgcn_global_load_lds(
          (gvptr)(A + (size_t)(m0 + r) * Kd + k0 + sx * 8),
          (lvptr)(&As(slot)[(p * 512 + w * 64) * 8]), 16, 0, 0);
      __builtin_amdgcn_global_load_lds(
          (gvptr)(Bm + (size_t)(n0 + r) * Kd + k0 + sx * 8),
          (lvptr)(&Bs(slot)[(p * 512 + w * 64) * 8]), 16, 0, 0);
    }
  };

  const f32x4 vzero = {0.f, 0.f, 0.f, 0.f};
  f32x4 acc[8][4];                // wave tile 128 x 64
#pragma unroll
  for (int i = 0; i < 8; ++i)
#pragma unroll
    for (int j = 0; j < 4; ++j) acc[i][j] = vzero;

  const int nkt = Kd >> 6;        // 16
  stage(0, 0);
  int cur = 0;
#pragma unroll 1
  for (int kt = 0; kt < nkt; ++kt) {
    if (kt + 1 < nkt) {
      stage(cur ^ 1, (kt + 1) * 64);         // 8 loads/thread stay in flight
      asm volatile("s_waitcnt vmcnt(8)" ::: "memory");
    } else {
      asm volatile("s_waitcnt vmcnt(0)" ::: "memory");
    }
    RAW_BARRIER();                           // slot[cur] fully staged

    __builtin_amdgcn_s_setprio(1);
#pragma unroll
    for (int ks = 0; ks < 2; ++ks) {
      short8 af[8], bf[4];
#pragma unroll
      for (int i = 0; i < 8; ++i) {
        int ra = wm * 128 + i * 16 + ln;
        af[i] = *(const short8*)&As(cur)[ra * 64 + (((ks * 4 + g) ^ (ra & 7)) * 8)];
      }
#pragma unroll
      for (int j = 0; j < 4; ++j) {
        int rb = wn * 64 + j * 16 + ln;
        bf[j] = *(const short8*)&Bs(cur)[rb * 64 + (((ks * 4 + g) ^ (rb & 7)) * 8)];
      }
#pragma unroll
      for (int i = 0; i < 8; ++i)
#pragma unroll
        for (int j = 0; j < 4; ++j)
          acc[i][j] = __builtin_amdgcn_mfma_f32_16x16x32_bf16(af[i], bf[j], acc[i][j], 0, 0, 0);
    }
    __builtin_amdgcn_s_setprio(0);

    asm volatile("s_waitcnt lgkmcnt(0)" ::: "memory");
    RAW_BARRIER();                           // release slot[cur] for restaging
    cur ^= 1;
  }

  if (n0 < 2048) {
    // q/k tile: RoPE rotate pairs (even/odd cols), write qkvb
#pragma unroll
    for (int i = 0; i < 8; ++i)
#pragma unroll
      for (int r = 0; r < 4; ++r) {
        int rowi = m0 + wm * 128 + i * 16 + g * 4 + r;
        int srow = rowi & (S_ - 1);
#pragma unroll
        for (int j = 0; j < 4; ++j) {
          int dk = j * 16 + ln;                       // wn*64 ≡ 0 (mod 64)
          float2 cs = cstab[srow * 32 + (dk >> 1)];
          float v = acc[i][j][r];
          float p = __shfl_xor(v, 1);
          float sn = (ln & 1) ? cs.y : -cs.y;
          float rot = fmaf(p, sn, v * cs.x);
          qkvb[(size_t)rowi * Nd + n0 + wn * 64 + j * 16 + ln] = f2bf(rot);
        }
      }
  } else {
    // v tile: 256x256 transpose via LDS (reuse all 128KB) -> Vt[b][h][dk][s]
    __syncthreads();               // staging LDS free (post final barrier)
    // write: tr[col][row ^ ((col&15)<<3)]
#pragma unroll
    for (int i = 0; i < 8; ++i)
#pragma unroll
      for (int j = 0; j < 4; ++j) {
        int col = wn * 64 + j * 16 + ln;
        int rowb = wm * 128 + i * 16 + g * 4;
        int s8 = (col & 15) << 3;
#pragma unroll
        for (int r = 0; r < 4; ++r)
          lds[col * 256 + ((rowb + r) ^ s8)] = f2bf(acc[i][j][r]);
      }
    __syncthreads();
    {
      int col = t >> 1, half = t & 1;        // 256 cols x 2 halves of 128 rows
      int vcol = (n0 - 2048) + col;          // 0..1023
      int hh = vcol >> 6, dk = vcol & 63;
      int bb = m0 >> 11, sb = m0 & 2047;
      u16* dstp = Vt + ((size_t)(bb * H_ + hh) * 64 + dk) * S_ + sb + half * 128;
      const u16* srcp = lds + col * 256;
      int s8 = (col & 15) << 3;
#pragma unroll
      for (int q = 0; q < 16; ++q)
        *(uint4*)(dstp + q * 8) = *(const uint4*)(srcp + (((half * 128 + q * 8) ^ s8)));
    }
  }
}

// ---------------- bf16 MFMA GEMM 64x64 (GEMM2): 1024 blocks = 4/CU ----------
__global__ __launch_bounds__(256) void gemm_small_mfma(const u16* __restrict__ A,
                                                       const u16* __restrict__ Bm,
                                                       float* __restrict__ C,
                                                       int Nd, int Kd) {
  __shared__ u16 As[2][64 * 64];
  __shared__ u16 Bs[2][64 * 64];
  const int t  = threadIdx.x;
  const int w  = t >> 6, l = t & 63;
  const int g  = l >> 4, ln = l & 15;
  const int wm = w >> 1, wn = w & 1;
  const int m0 = blockIdx.y * 64, n0 = blockIdx.x * 64;

  auto stage = [&](int buf, int k0) {
#pragma unroll
    for (int p = 0; p < 2; ++p) {
      int c = p * 256 + t;
      int r = c >> 3;
      int sx = (c & 7) ^ (r & 7);
      __builtin_amdgcn_global_load_lds(
          (gvptr)(A + (size_t)(m0 + r) * Kd + k0 + sx * 8),
          (lvptr)(&As[buf][(p * 256 + w * 64) * 8]), 16, 0, 0);
      __builtin_amdgcn_global_load_lds(
          (gvptr)(Bm + (size_t)(n0 + r) * Kd + k0 + sx * 8),
          (lvptr)(&Bs[buf][(p * 256 + w * 64) * 8]), 16, 0, 0);
    }
  };

  const f32x4 vzero = {0.f, 0.f, 0.f, 0.f};
  f32x4 acc[2][2];
#pragma unroll
  for (int i = 0; i < 2; ++i)
#pragma unroll
    for (int j = 0; j < 2; ++j) acc[i][j] = vzero;

  const int nkt = Kd >> 6;
  stage(0, 0);
  int cur = 0;
#pragma unroll 1
  for (int kt = 0; kt < nkt; ++kt) {
    if (kt + 1 < nkt) {
      stage(cur ^ 1, (kt + 1) * 64);       // 4 loads/thread in flight
      asm volatile("s_waitcnt vmcnt(4)" ::: "memory");
    } else {
      asm volatile("s_waitcnt vmcnt(0)" ::: "memory");
    }
    RAW_BARRIER();

    __builtin_amdgcn_s_setprio(1);
#pragma unroll
    for (int ks = 0; ks < 2; ++ks) {
      short8 af[2], bf[2];
#pragma unroll
      for (int i = 0; i < 2; ++i) {
        int ra = wm * 32 + i * 16 + ln;
        af[i] = *(const short8*)&As[cur][ra * 64 + (((ks * 4 + g) ^ (ra & 7)) * 8)];
        int rb = wn * 32 + i * 16 + ln;
        bf[i] = *(const short8*)&Bs[cur][rb * 64 + (((ks * 4 + g) ^ (rb & 7)) * 8)];
      }
#pragma unroll
      for (int i = 0; i < 2; ++i)
#pragma unroll
        for (int j = 0; j < 2; ++j)
          acc[i][j] = __builtin_amdgcn_mfma_f32_16x16x32_bf16(af[i], bf[j], acc[i][j], 0, 0, 0);
    }
    __builtin_amdgcn_s_setprio(0);

    asm volatile("s_waitcnt lgkmcnt(0)" ::: "memory");
    RAW_BARRIER();
    cur ^= 1;
  }

#pragma unroll
  for (int i = 0; i < 2; ++i)
#pragma unroll
    for (int j = 0; j < 2; ++j)
#pragma unroll
      for (int r = 0; r < 4; ++r)
        C[(size_t)(m0 + wm * 32 + i * 16 + g * 4 + r) * Nd + n0 + wn * 32 + j * 16 + ln]
            = acc[i][j][r];
}

// ---------------- flash attention: merged-pair single KV pass, KVBLK=128 ----
// (byte-identical to round 11 — XCD co-located, known-pass)
__global__ __launch_bounds__(512) void attn_mfma(const u16* __restrict__ qkvb,
                                                 const u16* __restrict__ Vt,
                                                 u16* __restrict__ attb) {
  __shared__ u16 Ks[2][128 * 64];   // [key][dk]
  __shared__ u16 Vs[2][64 * 128];   // [dk][key]
  const int t = threadIdx.x;
  const int w = t >> 6, l = t & 63;
  const int g = l >> 4, ln = l & 15;
  const int id = blockIdx.x;
  const int xcd = id & 7, slot = id >> 3;     // slot 0..31
  const int pair = xcd * 4 + (slot & 3);      // 0..31 = b*16+h
  const int bx = slot >> 2;                   // 0..7
  const int b = pair >> 4, h = pair & 15;
  const size_t bS = (size_t)b * S_;
  const u16* Kbase = qkvb + bS * NQKV + D_ + h * 64;          // row stride NQKV
  const u16* Vbase = Vt + (size_t)(b * H_ + h) * 64 * S_;     // row stride S_

  auto stage = [&](int buf, int k0) {
#pragma unroll
    for (int p = 0; p < 2; ++p) {
      int ck = p * 512 + t;                 // K chunk 0..1023
      int rk = ck >> 3, sk = (ck & 7) ^ SWZ(rk);
      __builtin_amdgcn_global_load_lds(
          (gvptr)(Kbase + (size_t)(k0 + rk) * NQKV + sk * 8),
          (lvptr)(&Ks[buf][(p * 512 + w * 64) * 8]), 16, 0, 0);
      int cv = p * 512 + t;                 // V chunk 0..1023
      int rv = cv >> 4, sv = (cv & 15) ^ (rv & 15);
      __builtin_amdgcn_global_load_lds(
          (gvptr)(Vbase + (size_t)rv * S_ + k0 + sv * 8),
          (lvptr)(&Vs[buf][(p * 512 + w * 64) * 8]), 16, 0, 0);
    }
  };

  const f32x4 vzero = {0.f, 0.f, 0.f, 0.f};

  const int tqH = 15 - bx, tqL = bx;
  const int q0H = tqH * 128, q0L = tqL * 128;
  const int nt = 16 - bx;                   // heavy pass length (128-key tiles)
  const int ntL = bx + 1;                   // light active tiles
  const int qgH = q0H + w * 16 + ln;
  const int qgL = q0L + w * 16 + ln;

  short8 qfH[2], qfL[2];
  {
    const u16* qr = qkvb + (bS + q0H + w * 16 + ln) * NQKV + h * 64;
    qfH[0] = *(const short8*)(qr + g * 8);
    qfH[1] = *(const short8*)(qr + 32 + g * 8);
    qr = qkvb + (bS + q0L + w * 16 + ln) * NQKV + h * 64;
    qfL[0] = *(const short8*)(qr + g * 8);
    qfL[1] = *(const short8*)(qr + 32 + g * 8);
#pragma unroll
    for (int kx = 0; kx < 2; ++kx)
#pragma unroll
      for (int e = 0; e < 8; ++e) {
        qfH[kx][e] = (short)f2bf(bf2f((u16)qfH[kx][e]) * QSCALE);
        qfL[kx][e] = (short)f2bf(bf2f((u16)qfL[kx][e]) * QSCALE);
      }
  }

  f32x4 oH[4], oL[4];
#pragma unroll
  for (int dt = 0; dt < 4; ++dt) { oH[dt] = vzero; oL[dt] = vzero; }
  float mH = -INFINITY, lH = 0.f, mL = -INFINITY, lL = 0.f;

  auto chain = [&](const short8* qf, f32x4* o, float& mrun, float& lrun,
                   int qg, bool maskTile, int k0, int cur) {
    f32x4 sacc[8];
#pragma unroll
    for (int st = 0; st < 8; ++st) sacc[st] = vzero;
    __builtin_amdgcn_s_setprio(1);
#pragma unroll
    for (int st = 0; st < 8; ++st) {
      const int pr = ((ln >> 2) << 3) + ((st & 1) << 2) + (ln & 3) + ((st >> 1) << 5);
#pragma unroll
      for (int ks = 0; ks < 2; ++ks) {
        short8 kf = *(const short8*)&Ks[cur][pr * 64 + (((ks * 4 + g) ^ SWZ(pr)) * 8)];
        sacc[st] = __builtin_amdgcn_mfma_f32_16x16x32_bf16(kf, qf[ks], sacc[st], 0, 0, 0);
      }
    }
    __builtin_amdgcn_s_setprio(0);

    float tmax = -INFINITY;
    if (maskTile) {
#pragma unroll
      for (int st = 0; st < 8; ++st)
#pragma unroll
        for (int r = 0; r < 4; ++r) {
          int key = k0 + g * 8 + ((st & 1) << 2) + r + ((st >> 1) << 5);
          if (key > qg) sacc[st][r] = -INFINITY;
          tmax = fmaxf(tmax, sacc[st][r]);
        }
    } else {
#pragma unroll
      for (int st = 0; st < 8; ++st)
#pragma unroll
        for (int r = 0; r < 4; ++r) tmax = fmaxf(tmax, sacc[st][r]);
    }
    tmax = fmaxf(tmax, __shfl_xor(tmax, 16));
    tmax = fmaxf(tmax, __shfl_xor(tmax, 32));
    float al = 1.f, mnew = mrun;
    if (!__all(tmax <= mrun + 8.0f)) {       // defer-max (THR=8 in log2 units)
      mnew = fmaxf(mrun, tmax);
      al = EXP2F(mrun - mnew);
#pragma unroll
      for (int r = 0; r < 4; ++r) {
        float srs = __shfl(al, g * 4 + r);
#pragma unroll
        for (int dt = 0; dt < 4; ++dt) o[dt][r] *= srs;
      }
    }
    float lsum = 0.f;
#pragma unroll
    for (int st = 0; st < 8; ++st)
#pragma unroll
      for (int r = 0; r < 4; ++r) {
        float pe = EXP2F(sacc[st][r] - mnew);
        sacc[st][r] = pe;
        lsum += pe;
      }
    lsum += __shfl_xor(lsum, 16);
    lsum += __shfl_xor(lsum, 32);
    lrun = lrun * al + lsum;
    mrun = mnew;

    union { u32 u[4]; short8 v; } pa[4];
#pragma unroll
    for (int ks = 0; ks < 4; ++ks) {
      pa[ks].u[0] = cvtpk_bf16(sacc[2 * ks][0], sacc[2 * ks][1]);
      pa[ks].u[1] = cvtpk_bf16(sacc[2 * ks][2], sacc[2 * ks][3]);
      pa[ks].u[2] = cvtpk_bf16(sacc[2 * ks + 1][0], sacc[2 * ks + 1][1]);
      pa[ks].u[3] = cvtpk_bf16(sacc[2 * ks + 1][2], sacc[2 * ks + 1][3]);
    }

    __builtin_amdgcn_s_setprio(1);
#pragma unroll
    for (int ks = 0; ks < 4; ++ks)
#pragma unroll
      for (int dt = 0; dt < 4; ++dt) {
        const int dr = dt * 16 + ln;
        short8 vf = *(const short8*)&Vs[cur][dr * 128 + (((ks * 4 + g) ^ (dr & 15)) * 8)];
        o[dt] = __builtin_amdgcn_mfma_f32_16x16x32_bf16(pa[ks].v, vf, o[dt], 0, 0, 0);
      }
    __builtin_amdgcn_s_setprio(0);
  };

  stage(0, 0);
  int cur = 0;
#pragma unroll 1
  for (int kt = 0; kt < nt; ++kt) {
    const int k0 = kt * 128;
    if (kt + 1 < nt) {
      stage(cur ^ 1, k0 + 128);            // 4 loads/thread in flight
      asm volatile("s_waitcnt vmcnt(4)" ::: "memory");
    } else {
      asm volatile("s_waitcnt vmcnt(0)" ::: "memory");
    }
    RAW_BARRIER();                         // buf[cur] staged

    chain(qfH, oH, mH, lH, qgH, kt == nt - 1, k0, cur);
    if (kt < ntL)
      chain(qfL, oL, mL, lL, qgL, kt == tqL, k0, cur);

    asm volatile("s_waitcnt lgkmcnt(0)" ::: "memory");
    RAW_BARRIER();                         // release buf[cur]
    cur ^= 1;
  }

  // epilogues
  {
    float linv = 1.f / lH;
#pragma unroll
    for (int r = 0; r < 4; ++r) {
      float ir = __shfl(linv, g * 4 + r);
      size_t row = bS + q0H + w * 16 + g * 4 + r;
#pragma unroll
      for (int dt = 0; dt < 4; ++dt)
        attb[row * D_ + h * 64 + dt * 16 + ln] = f2bf(oH[dt][r] * ir);
    }
  }
  {
    float linv = 1.f / lL;
#pragma unroll
    for (int r = 0; r < 4; ++r) {
      float ir = __shfl(linv, g * 4 + r);
      size_t row = bS + q0L + w * 16 + g * 4 + r;
#pragma unroll
      for (int dt = 0; dt < 4; ++dt)
        attb[row * D_ + h * 64 + dt * 16 + ln] = f2bf(oL[dt][r] * ir);
    }
  }
}

// ---------------------------------------------------------------------------
extern "C" void kernel_launch(void* const* d_in, const int* in_sizes, int n_in,
                              void* d_out, int out_size, void* d_ws, size_t ws_size,
                              hipStream_t stream) {
  (void)in_sizes; (void)n_in; (void)out_size; (void)ws_size;
  const float* x   = (const float*)d_in[0];
  const int*   pos = (const int*)d_in[1];
  const float* w   = (const float*)d_in[2];   // (3,H,DK,D)
  const float* wo  = (const float*)d_in[3];   // (D, H*DK)
  float* out = (float*)d_out;

  u16* qkvb = (u16*)d_ws;                        // [4096][3072] (v-part unused)
  u16* Vt   = qkvb + (size_t)M_ * NQKV;          // [2][16][64][2048]
  u16* attb = Vt + (size_t)B_ * H_ * 64 * S_;    // [4096][1024]
  u16* xb   = attb + (size_t)M_ * D_;            // [4096][1024]
  u16* wb   = xb + (size_t)M_ * D_;              // [3072][1024]  (contiguous after xb)
  u16* wob  = wb + (size_t)NQKV * D_;            // [1024][1024]  (contiguous after wb)
  float2* cstab = (float2*)(wob + (size_t)D_ * D_);  // [2048][32]

  cvt_all_kernel<<<NCVT / 256 + 256, 256, 0, stream>>>(x, w, wo, xb, pos, cstab);

  gemm_qkv_mfma<<<dim3(192), 512, 0, stream>>>(xb, wb, qkvb, Vt, cstab);

  attn_mfma<<<dim3(256), 512, 0, stream>>>(qkvb, Vt, attb);

  gemm_small_mfma<<<dim3(D_ / 64, M_ / 64), 256, 0, stream>>>(
      attb, wob, out, D_, D_);
}